// Round 2
// baseline (487.286 us; speedup 1.0000x reference)
//
#include <hip/hip_runtime.h>

#define DM 1024
#define HEADS 16
#define DH 64
#define BB 4
#define LL 2048
#define MROWS (BB * LL) /* 8192 */

typedef __bf16 bf16x8 __attribute__((ext_vector_type(8)));
typedef float f32x4 __attribute__((ext_vector_type(4)));

__device__ __forceinline__ unsigned short f2bf(float f) {
  union { float f; unsigned int u; } v;
  v.f = f;
  unsigned int u = v.u;
  u += 0x7FFFu + ((u >> 16) & 1u);
  return (unsigned short)(u >> 16);
}
__device__ __forceinline__ unsigned int pack2(float a, float b) {
  return (unsigned int)f2bf(a) | ((unsigned int)f2bf(b) << 16);
}

// ---------------------------------------------------------------------------
// Weight transpose + bf16 convert: WT[n][k] = bf16(W[k][n]), 1024x1024
// ---------------------------------------------------------------------------
__global__ __launch_bounds__(256) void transpose_w_kernel(
    const float* __restrict__ W, unsigned short* __restrict__ WT) {
  __shared__ float tile[32][33];
  const int tx = threadIdx.x & 31;
  const int ty = threadIdx.x >> 5;
  const int x0 = blockIdx.x * 32;
  const int y0 = blockIdx.y * 32;
#pragma unroll
  for (int i = 0; i < 32; i += 8)
    tile[ty + i][tx] = W[(size_t)(y0 + ty + i) * DM + x0 + tx];
  __syncthreads();
#pragma unroll
  for (int i = 0; i < 32; i += 8)
    WT[(size_t)(x0 + ty + i) * DM + y0 + tx] = f2bf(tile[tx][ty + i]);
}

// ---------------------------------------------------------------------------
// GEMM: C = A(8192xK) * BT^T + bias.  A fp32 (AMODE 0) or bf16 (AMODE 1).
// OUTMODE 0: bf16 out, head layout [B,H,L,DH].  OUTMODE 1: fp32 row-major.
// Tile 128x128, BK=32, 256 threads (4 waves, each 64x64 via 4x4 16x16 frags).
// ---------------------------------------------------------------------------
template <int AMODE, int OUTMODE>
__device__ __forceinline__ void gemm_body(
    const void* __restrict__ Aptr, const unsigned short* __restrict__ BT,
    const float* __restrict__ bias, void* __restrict__ Cptr,
    int m0, int n0) {
  constexpr int K = DM, N = DM;
  __shared__ unsigned short As[128][40];
  __shared__ unsigned short Bs[128][40];
  const int t = threadIdx.x;
  const int lane = t & 63;
  const int w = t >> 6;
  const int wr = w >> 1, wc = w & 1;
  const int fr = lane & 15, kg = lane >> 4;

  // staging decomposition for a [128][32] bf16 tile: 512 chunks of 8 elems
  const int c0 = t, c1 = t + 256;
  const int row0 = c0 >> 2, kc0 = (c0 & 3) * 8;
  const int row1 = c1 >> 2, kc1 = (c1 & 3) * 8;

  f32x4 acc[4][4] = {};

  for (int kt = 0; kt < K / 32; ++kt) {
    const int k0 = kt * 32;
    if (AMODE == 0) {
      const float* A = (const float*)Aptr;
      {
        const float* src = A + (size_t)(m0 + row0) * K + k0 + kc0;
        float4 x = *(const float4*)src;
        float4 y = *(const float4*)(src + 4);
        uint4 p = {pack2(x.x, x.y), pack2(x.z, x.w), pack2(y.x, y.y), pack2(y.z, y.w)};
        *(uint4*)&As[row0][kc0] = p;
      }
      {
        const float* src = A + (size_t)(m0 + row1) * K + k0 + kc1;
        float4 x = *(const float4*)src;
        float4 y = *(const float4*)(src + 4);
        uint4 p = {pack2(x.x, x.y), pack2(x.z, x.w), pack2(y.x, y.y), pack2(y.z, y.w)};
        *(uint4*)&As[row1][kc1] = p;
      }
    } else {
      const unsigned short* A = (const unsigned short*)Aptr;
      *(uint4*)&As[row0][kc0] = *(const uint4*)(A + (size_t)(m0 + row0) * K + k0 + kc0);
      *(uint4*)&As[row1][kc1] = *(const uint4*)(A + (size_t)(m0 + row1) * K + k0 + kc1);
    }
    *(uint4*)&Bs[row0][kc0] = *(const uint4*)(BT + (size_t)(n0 + row0) * K + k0 + kc0);
    *(uint4*)&Bs[row1][kc1] = *(const uint4*)(BT + (size_t)(n0 + row1) * K + k0 + kc1);
    __syncthreads();

    bf16x8 af[4], bfr[4];
#pragma unroll
    for (int i = 0; i < 4; i++)
      af[i] = *(const bf16x8*)&As[wr * 64 + i * 16 + fr][kg * 8];
#pragma unroll
    for (int i = 0; i < 4; i++)
      bfr[i] = *(const bf16x8*)&Bs[wc * 64 + i * 16 + fr][kg * 8];
#pragma unroll
    for (int i = 0; i < 4; i++)
#pragma unroll
      for (int j = 0; j < 4; j++)
        acc[i][j] = __builtin_amdgcn_mfma_f32_16x16x32_bf16(af[i], bfr[j], acc[i][j], 0, 0, 0);
    __syncthreads();
  }

#pragma unroll
  for (int j = 0; j < 4; j++) {
    const int gcol = n0 + wc * 64 + j * 16 + fr;
    const float bv = bias[gcol];
#pragma unroll
    for (int i = 0; i < 4; i++) {
      const int grow0 = m0 + wr * 64 + i * 16 + kg * 4;
#pragma unroll
      for (int r = 0; r < 4; r++) {
        const float val = acc[i][j][r] + bv;
        const int grow = grow0 + r;
        if (OUTMODE == 0) {
          const int b = grow >> 11, l = grow & 2047;
          const int h = gcol >> 6, dh = gcol & 63;
          ((unsigned short*)Cptr)[(((size_t)(b * HEADS + h) * LL + l) << 6) + dh] = f2bf(val);
        } else {
          ((float*)Cptr)[(size_t)grow * N + gcol] = val;
        }
      }
    }
  }
}

__global__ __launch_bounds__(256) void qkv_gemm_kernel(
    const float* __restrict__ q, const float* __restrict__ k, const float* __restrict__ v,
    const unsigned short* __restrict__ WqT, const unsigned short* __restrict__ WkT,
    const unsigned short* __restrict__ WvT,
    const float* __restrict__ bq, const float* __restrict__ bk, const float* __restrict__ bv,
    unsigned short* __restrict__ Qh, unsigned short* __restrict__ Kh,
    unsigned short* __restrict__ Vh) {
  const int z = blockIdx.z;
  const float* A;
  const unsigned short* BT;
  const float* bias;
  unsigned short* C;
  if (z == 0) { A = q; BT = WqT; bias = bq; C = Qh; }
  else if (z == 1) { A = k; BT = WkT; bias = bk; C = Kh; }
  else { A = v; BT = WvT; bias = bv; C = Vh; }
  gemm_body<0, 0>(A, BT, bias, C, blockIdx.y * 128, blockIdx.x * 128);
}

__global__ __launch_bounds__(256) void oproj_gemm_kernel(
    const unsigned short* __restrict__ Oc, const unsigned short* __restrict__ WoT,
    const float* __restrict__ bo, float* __restrict__ out) {
  gemm_body<1, 1>(Oc, WoT, bo, out, blockIdx.y * 128, blockIdx.x * 128);
}

// ---------------------------------------------------------------------------
// Causal flash attention.  Grid (qtile=32, bh=64).  Block 256 = 4 waves.
// Each wave: 16 q-rows.  KV tiles of 64.  Dh=64.
// ---------------------------------------------------------------------------
__global__ __launch_bounds__(256) void attn_kernel(
    const unsigned short* __restrict__ Qh, const unsigned short* __restrict__ Kh,
    const unsigned short* __restrict__ Vh, unsigned short* __restrict__ O) {
  __shared__ unsigned short Ks[64][72];
  __shared__ unsigned short VTs[64][72];   // [dh][kv]
  __shared__ unsigned short Ps[4][16][72]; // per-wave P: [q16][kv64]
  const int t = threadIdx.x, lane = t & 63, w = t >> 6;
  const int fr = lane & 15, kg = lane >> 4;
  const int bh = blockIdx.y, qtile = blockIdx.x;
  const int q0 = qtile * 64;
  const size_t base = (size_t)bh * LL * DH;

  // Q fragments (held in registers for the whole kernel)
  bf16x8 aq[2];
  {
    const unsigned short* Qb = Qh + base + (size_t)(q0 + w * 16 + fr) * DH;
    aq[0] = *(const bf16x8*)(Qb + kg * 8);
    aq[1] = *(const bf16x8*)(Qb + 32 + kg * 8);
  }

  float m_run[4], l_run[4];
  f32x4 oacc[4] = {};
#pragma unroll
  for (int r = 0; r < 4; r++) { m_run[r] = -INFINITY; l_run[r] = 0.f; }

  // staging decomposition for a [64][64] bf16 tile: 512 chunks of 8 elems
  const int rA = t >> 3, kA = (t & 7) * 8;  // rows 0..31, cols 0..56
  const int rB = rA + 32;                   // rows 32..63

  for (int jt = 0; jt <= qtile; ++jt) {
    const unsigned short* Kt = Kh + base + (size_t)(jt * 64) * DH;
    const unsigned short* Vt = Vh + base + (size_t)(jt * 64) * DH;
    *(uint4*)&Ks[rA][kA] = *(const uint4*)(Kt + rA * 64 + kA);
    *(uint4*)&Ks[rB][kA] = *(const uint4*)(Kt + rB * 64 + kA);
    {
      uint4 vv = *(const uint4*)(Vt + rA * 64 + kA);
      const unsigned short* pv = (const unsigned short*)&vv;
#pragma unroll
      for (int e = 0; e < 8; e++) VTs[kA + e][rA] = pv[e];
    }
    {
      uint4 vv = *(const uint4*)(Vt + rB * 64 + kA);
      const unsigned short* pv = (const unsigned short*)&vv;
#pragma unroll
      for (int e = 0; e < 8; e++) VTs[kA + e][rB] = pv[e];
    }
    __syncthreads();

    // S = Q K^T  (16 q x 64 kv per wave)
    f32x4 s[4];
#pragma unroll
    for (int ni = 0; ni < 4; ni++) {
      bf16x8 b0 = *(const bf16x8*)&Ks[ni * 16 + fr][kg * 8];
      bf16x8 b1 = *(const bf16x8*)&Ks[ni * 16 + fr][32 + kg * 8];
      f32x4 z = {};
      z = __builtin_amdgcn_mfma_f32_16x16x32_bf16(aq[0], b0, z, 0, 0, 0);
      s[ni] = __builtin_amdgcn_mfma_f32_16x16x32_bf16(aq[1], b1, z, 0, 0, 0);
    }
    // scale + causal mask (C layout: row = kg*4+r, col = ni*16+fr)
    const int qrow = q0 + w * 16 + kg * 4;
    const int kv0 = jt * 64;
#pragma unroll
    for (int ni = 0; ni < 4; ni++)
#pragma unroll
      for (int r = 0; r < 4; r++) {
        float val = s[ni][r] * 0.125f;
        if (jt == qtile && (kv0 + ni * 16 + fr) > (qrow + r)) val = -1e30f;
        s[ni][r] = val;
      }
    // online softmax (rows live across the 16 lanes sharing kg)
#pragma unroll
    for (int r = 0; r < 4; r++) {
      float tm = fmaxf(fmaxf(s[0][r], s[1][r]), fmaxf(s[2][r], s[3][r]));
#pragma unroll
      for (int off = 1; off < 16; off <<= 1) tm = fmaxf(tm, __shfl_xor(tm, off));
      const float mnew = fmaxf(m_run[r], tm);
      const float corr = __expf(m_run[r] - mnew);
      float rs = 0.f;
#pragma unroll
      for (int ni = 0; ni < 4; ni++) {
        float p = __expf(s[ni][r] - mnew);
        s[ni][r] = p;
        rs += p;
      }
#pragma unroll
      for (int off = 1; off < 16; off <<= 1) rs += __shfl_xor(rs, off);
      l_run[r] = l_run[r] * corr + rs;
      m_run[r] = mnew;
#pragma unroll
      for (int di = 0; di < 4; di++) oacc[di][r] *= corr;
    }
    // P -> LDS (to reach A-fragment layout)
#pragma unroll
    for (int ni = 0; ni < 4; ni++)
#pragma unroll
      for (int r = 0; r < 4; r++)
        Ps[w][kg * 4 + r][ni * 16 + fr] = f2bf(s[ni][r]);
    __syncthreads();
    // PV
    bf16x8 ap0 = *(const bf16x8*)&Ps[w][fr][kg * 8];
    bf16x8 ap1 = *(const bf16x8*)&Ps[w][fr][32 + kg * 8];
#pragma unroll
    for (int di = 0; di < 4; di++) {
      bf16x8 v0 = *(const bf16x8*)&VTs[di * 16 + fr][kg * 8];
      bf16x8 v1 = *(const bf16x8*)&VTs[di * 16 + fr][32 + kg * 8];
      oacc[di] = __builtin_amdgcn_mfma_f32_16x16x32_bf16(ap0, v0, oacc[di], 0, 0, 0);
      oacc[di] = __builtin_amdgcn_mfma_f32_16x16x32_bf16(ap1, v1, oacc[di], 0, 0, 0);
    }
    __syncthreads();
  }

  // epilogue: O[b][l][h*64+dh] bf16
  const int b = bh >> 4, h = bh & 15;
#pragma unroll
  for (int di = 0; di < 4; di++)
#pragma unroll
    for (int r = 0; r < 4; r++) {
      const int qg = q0 + w * 16 + kg * 4 + r;
      const int dh = di * 16 + fr;
      const float val = oacc[di][r] / l_run[r];
      O[((size_t)(b * LL + qg) * DM) + h * DH + dh] = f2bf(val);
    }
}

// ---------------------------------------------------------------------------
extern "C" void kernel_launch(void* const* d_in, const int* in_sizes, int n_in,
                              void* d_out, int out_size, void* d_ws, size_t ws_size,
                              hipStream_t stream) {
  (void)in_sizes; (void)n_in; (void)out_size; (void)ws_size;
  const float* q  = (const float*)d_in[0];
  const float* k  = (const float*)d_in[1];
  const float* v  = (const float*)d_in[2];
  const float* Wq = (const float*)d_in[3];
  const float* bq = (const float*)d_in[4];
  const float* Wk = (const float*)d_in[5];
  const float* bk = (const float*)d_in[6];
  const float* Wv = (const float*)d_in[7];
  const float* bv = (const float*)d_in[8];
  const float* Wo = (const float*)d_in[9];
  const float* bo = (const float*)d_in[10];

  char* ws = (char*)d_ws;
  const size_t WSZ = (size_t)DM * DM * 2;          // 2 MB per transposed weight
  const size_t HSZ = (size_t)MROWS * DM * 2;       // 16 MB per bf16 activation
  unsigned short* WqT = (unsigned short*)(ws);
  unsigned short* WkT = (unsigned short*)(ws + WSZ);
  unsigned short* WvT = (unsigned short*)(ws + 2 * WSZ);
  unsigned short* WoT = (unsigned short*)(ws + 3 * WSZ);
  unsigned short* Qh  = (unsigned short*)(ws + 4 * WSZ);
  unsigned short* Kh  = (unsigned short*)(ws + 4 * WSZ + HSZ);
  unsigned short* Vh  = (unsigned short*)(ws + 4 * WSZ + 2 * HSZ);
  unsigned short* Oc  = (unsigned short*)(ws + 4 * WSZ + 3 * HSZ);

  dim3 tgrid(32, 32);
  transpose_w_kernel<<<tgrid, 256, 0, stream>>>(Wq, WqT);
  transpose_w_kernel<<<tgrid, 256, 0, stream>>>(Wk, WkT);
  transpose_w_kernel<<<tgrid, 256, 0, stream>>>(Wv, WvT);
  transpose_w_kernel<<<tgrid, 256, 0, stream>>>(Wo, WoT);

  qkv_gemm_kernel<<<dim3(DM / 128, MROWS / 128, 3), 256, 0, stream>>>(
      q, k, v, WqT, WkT, WvT, bq, bk, bv, Qh, Kh, Vh);

  attn_kernel<<<dim3(LL / 64, BB * HEADS), 256, 0, stream>>>(Qh, Kh, Vh, Oc);

  oproj_gemm_kernel<<<dim3(DM / 128, MROWS / 128), 256, 0, stream>>>(
      Oc, WoT, bo, (float*)d_out);
}

// Round 3
// 406.198 us; speedup vs baseline: 1.1996x; 1.1996x over previous
//
#include <hip/hip_runtime.h>

#define DM 1024
#define HEADS 16
#define DH 64
#define BB 4
#define LL 2048
#define MROWS (BB * LL) /* 8192 */

typedef __bf16 bf16x8 __attribute__((ext_vector_type(8)));
typedef float f32x4 __attribute__((ext_vector_type(4)));

__device__ __forceinline__ unsigned short f2bf(float f) {
  union { float f; unsigned int u; } v;
  v.f = f;
  unsigned int u = v.u;
  u += 0x7FFFu + ((u >> 16) & 1u);
  return (unsigned short)(u >> 16);
}
__device__ __forceinline__ unsigned int pack2(float a, float b) {
  return (unsigned int)f2bf(a) | ((unsigned int)f2bf(b) << 16);
}

// ---------------------------------------------------------------------------
// Weight transpose + bf16 convert: WT[n][k] = bf16(W[k][n]), 1024x1024
// ---------------------------------------------------------------------------
__global__ __launch_bounds__(256) void transpose_w_kernel(
    const float* __restrict__ W, unsigned short* __restrict__ WT) {
  __shared__ float tile[32][33];
  const int tx = threadIdx.x & 31;
  const int ty = threadIdx.x >> 5;
  const int x0 = blockIdx.x * 32;
  const int y0 = blockIdx.y * 32;
#pragma unroll
  for (int i = 0; i < 32; i += 8)
    tile[ty + i][tx] = W[(size_t)(y0 + ty + i) * DM + x0 + tx];
  __syncthreads();
#pragma unroll
  for (int i = 0; i < 32; i += 8)
    WT[(size_t)(x0 + ty + i) * DM + y0 + tx] = f2bf(tile[tx][ty + i]);
}

// ---------------------------------------------------------------------------
// GEMM: C = A(8192xK) * BT^T + bias.  A fp32 (AMODE 0) or bf16 (AMODE 1).
// OUTMODE 0: bf16 out, head layout [B,H,L,DH].
// OUTMODE 1: fp32 row-major.
// OUTMODE 2: bf16 out, TRANSPOSED head layout [B,H,DH,L]  (for V)
// Tile 128x128, BK=32, 256 threads (4 waves, each 64x64 via 4x4 16x16 frags).
// ---------------------------------------------------------------------------
template <int AMODE, int OUTMODE>
__device__ __forceinline__ void gemm_body(
    const void* __restrict__ Aptr, const unsigned short* __restrict__ BT,
    const float* __restrict__ bias, void* __restrict__ Cptr,
    int m0, int n0) {
  constexpr int K = DM, N = DM;
  __shared__ unsigned short As[128][40];
  __shared__ unsigned short Bs[128][40];
  const int t = threadIdx.x;
  const int lane = t & 63;
  const int w = t >> 6;
  const int wr = w >> 1, wc = w & 1;
  const int fr = lane & 15, kg = lane >> 4;

  // staging decomposition for a [128][32] bf16 tile: 512 chunks of 8 elems
  const int c0 = t, c1 = t + 256;
  const int row0 = c0 >> 2, kc0 = (c0 & 3) * 8;
  const int row1 = c1 >> 2, kc1 = (c1 & 3) * 8;

  f32x4 acc[4][4] = {};

  for (int kt = 0; kt < K / 32; ++kt) {
    const int k0 = kt * 32;
    if (AMODE == 0) {
      const float* A = (const float*)Aptr;
      {
        const float* src = A + (size_t)(m0 + row0) * K + k0 + kc0;
        float4 x = *(const float4*)src;
        float4 y = *(const float4*)(src + 4);
        uint4 p = {pack2(x.x, x.y), pack2(x.z, x.w), pack2(y.x, y.y), pack2(y.z, y.w)};
        *(uint4*)&As[row0][kc0] = p;
      }
      {
        const float* src = A + (size_t)(m0 + row1) * K + k0 + kc1;
        float4 x = *(const float4*)src;
        float4 y = *(const float4*)(src + 4);
        uint4 p = {pack2(x.x, x.y), pack2(x.z, x.w), pack2(y.x, y.y), pack2(y.z, y.w)};
        *(uint4*)&As[row1][kc1] = p;
      }
    } else {
      const unsigned short* A = (const unsigned short*)Aptr;
      *(uint4*)&As[row0][kc0] = *(const uint4*)(A + (size_t)(m0 + row0) * K + k0 + kc0);
      *(uint4*)&As[row1][kc1] = *(const uint4*)(A + (size_t)(m0 + row1) * K + k0 + kc1);
    }
    *(uint4*)&Bs[row0][kc0] = *(const uint4*)(BT + (size_t)(n0 + row0) * K + k0 + kc0);
    *(uint4*)&Bs[row1][kc1] = *(const uint4*)(BT + (size_t)(n0 + row1) * K + k0 + kc1);
    __syncthreads();

    bf16x8 af[4], bfr[4];
#pragma unroll
    for (int i = 0; i < 4; i++)
      af[i] = *(const bf16x8*)&As[wr * 64 + i * 16 + fr][kg * 8];
#pragma unroll
    for (int i = 0; i < 4; i++)
      bfr[i] = *(const bf16x8*)&Bs[wc * 64 + i * 16 + fr][kg * 8];
#pragma unroll
    for (int i = 0; i < 4; i++)
#pragma unroll
      for (int j = 0; j < 4; j++)
        acc[i][j] = __builtin_amdgcn_mfma_f32_16x16x32_bf16(af[i], bfr[j], acc[i][j], 0, 0, 0);
    __syncthreads();
  }

#pragma unroll
  for (int j = 0; j < 4; j++) {
    const int gcol = n0 + wc * 64 + j * 16 + fr;
    const float bv = bias[gcol];
    const int h = gcol >> 6, dh = gcol & 63;
#pragma unroll
    for (int i = 0; i < 4; i++) {
      const int grow0 = m0 + wr * 64 + i * 16 + kg * 4;
      if (OUTMODE == 2) {
        const int b = grow0 >> 11, l = grow0 & 2047;
        uint2 pk;
        pk.x = pack2(acc[i][j][0] + bv, acc[i][j][1] + bv);
        pk.y = pack2(acc[i][j][2] + bv, acc[i][j][3] + bv);
        *(uint2*)((unsigned short*)Cptr +
                  ((size_t)((b * HEADS + h) * DH + dh)) * LL + l) = pk;
      } else {
#pragma unroll
        for (int r = 0; r < 4; r++) {
          const float val = acc[i][j][r] + bv;
          const int grow = grow0 + r;
          if (OUTMODE == 0) {
            const int b = grow >> 11, l = grow & 2047;
            ((unsigned short*)Cptr)[(((size_t)(b * HEADS + h) * LL + l) << 6) + dh] = f2bf(val);
          } else {
            ((float*)Cptr)[(size_t)grow * N + gcol] = val;
          }
        }
      }
    }
  }
}

__global__ __launch_bounds__(256) void qk_gemm_kernel(
    const float* __restrict__ q, const float* __restrict__ k,
    const unsigned short* __restrict__ WqT, const unsigned short* __restrict__ WkT,
    const float* __restrict__ bq, const float* __restrict__ bk,
    unsigned short* __restrict__ Qh, unsigned short* __restrict__ Kh) {
  const int z = blockIdx.z;
  const float* A = z ? k : q;
  const unsigned short* BT = z ? WkT : WqT;
  const float* bias = z ? bk : bq;
  unsigned short* C = z ? Kh : Qh;
  gemm_body<0, 0>(A, BT, bias, C, blockIdx.y * 128, blockIdx.x * 128);
}

__global__ __launch_bounds__(256) void v_gemm_kernel(
    const float* __restrict__ v, const unsigned short* __restrict__ WvT,
    const float* __restrict__ bv, unsigned short* __restrict__ VhT) {
  gemm_body<0, 2>(v, WvT, bv, VhT, blockIdx.y * 128, blockIdx.x * 128);
}

__global__ __launch_bounds__(256) void oproj_gemm_kernel(
    const unsigned short* __restrict__ Oc, const unsigned short* __restrict__ WoT,
    const float* __restrict__ bo, float* __restrict__ out) {
  gemm_body<1, 1>(Oc, WoT, bo, out, blockIdx.y * 128, blockIdx.x * 128);
}

// ---------------------------------------------------------------------------
// Causal flash attention.  Grid (qtile=32, bh=64).  Block 256 = 4 waves.
// Each wave: 16 q-rows.  KV tiles of 64.  Dh=64.
// K staged row-major [kv][d]; V staged from pre-transposed VhT as [d][kv].
// LDS row stride 76 (2-way max bank aliasing).  2 barriers/iter.
// Next tile prefetched into registers during compute.
// ---------------------------------------------------------------------------
#define PAD 76
__global__ __launch_bounds__(256) void attn_kernel(
    const unsigned short* __restrict__ Qh, const unsigned short* __restrict__ Kh,
    const unsigned short* __restrict__ VhT, unsigned short* __restrict__ O) {
  __shared__ unsigned short Ks[64][PAD];
  __shared__ unsigned short VTs[64][PAD];  // [dh][kv]
  __shared__ unsigned short Ps[4][16][PAD];
  const int t = threadIdx.x, lane = t & 63, w = t >> 6;
  const int fr = lane & 15, kg = lane >> 4;
  const int bh = blockIdx.y;
  const int qtile = (int)gridDim.x - 1 - (int)blockIdx.x;  // longest-first
  const int q0 = qtile * 64;
  const size_t base = (size_t)bh * LL * DH;

  // Q fragments (held in registers for the whole kernel)
  bf16x8 aq[2];
  {
    const unsigned short* Qb = Qh + base + (size_t)(q0 + w * 16 + fr) * DH;
    aq[0] = *(const bf16x8*)(Qb + kg * 8);
    aq[1] = *(const bf16x8*)(Qb + 32 + kg * 8);
  }

  float m_run[4], l_run[4];
  f32x4 oacc[4] = {};
#pragma unroll
  for (int r = 0; r < 4; r++) { m_run[r] = -INFINITY; l_run[r] = 0.f; }

  // staging decomposition for a [64][64] bf16 tile: 512 chunks of 8 elems
  const int rA = t >> 3, kA = (t & 7) * 8;  // rows 0..31, cols 0..56
  const int rB = rA + 32;                   // rows 32..63

  const unsigned short* Kb = Kh + base;
  const unsigned short* Vb = VhT + base;  // [dh][kv]

  // prefetch tile 0 into registers
  uint4 kra = *(const uint4*)(Kb + (size_t)rA * DH + kA);
  uint4 krb = *(const uint4*)(Kb + (size_t)rB * DH + kA);
  uint4 vra = *(const uint4*)(Vb + (size_t)rA * LL + kA);
  uint4 vrb = *(const uint4*)(Vb + (size_t)rB * LL + kA);

  for (int jt = 0; jt <= qtile; ++jt) {
    *(uint4*)&Ks[rA][kA] = kra;
    *(uint4*)&Ks[rB][kA] = krb;
    *(uint4*)&VTs[rA][kA] = vra;
    *(uint4*)&VTs[rB][kA] = vrb;
    __syncthreads();

    // issue next tile's loads (latency hides under compute below)
    if (jt < qtile) {
      const int kv1 = (jt + 1) * 64;
      kra = *(const uint4*)(Kb + (size_t)(kv1 + rA) * DH + kA);
      krb = *(const uint4*)(Kb + (size_t)(kv1 + rB) * DH + kA);
      vra = *(const uint4*)(Vb + (size_t)rA * LL + kv1 + kA);
      vrb = *(const uint4*)(Vb + (size_t)rB * LL + kv1 + kA);
    }

    // S = Q K^T  (16 q x 64 kv per wave)
    f32x4 s[4];
#pragma unroll
    for (int ni = 0; ni < 4; ni++) {
      bf16x8 b0 = *(const bf16x8*)&Ks[ni * 16 + fr][kg * 8];
      bf16x8 b1 = *(const bf16x8*)&Ks[ni * 16 + fr][32 + kg * 8];
      f32x4 z = {};
      z = __builtin_amdgcn_mfma_f32_16x16x32_bf16(aq[0], b0, z, 0, 0, 0);
      s[ni] = __builtin_amdgcn_mfma_f32_16x16x32_bf16(aq[1], b1, z, 0, 0, 0);
    }
    // scale + causal mask (C layout: row = kg*4+r, col = ni*16+fr)
    const int qrow = q0 + w * 16 + kg * 4;
    const int kv0 = jt * 64;
#pragma unroll
    for (int ni = 0; ni < 4; ni++)
#pragma unroll
      for (int r = 0; r < 4; r++) {
        float val = s[ni][r] * 0.125f;
        if (jt == qtile && (kv0 + ni * 16 + fr) > (qrow + r)) val = -1e30f;
        s[ni][r] = val;
      }
    // online softmax (rows live across the 16 lanes sharing kg)
#pragma unroll
    for (int r = 0; r < 4; r++) {
      float tm = fmaxf(fmaxf(s[0][r], s[1][r]), fmaxf(s[2][r], s[3][r]));
#pragma unroll
      for (int off = 1; off < 16; off <<= 1) tm = fmaxf(tm, __shfl_xor(tm, off));
      const float mnew = fmaxf(m_run[r], tm);
      const float corr = __expf(m_run[r] - mnew);
      float rs = 0.f;
#pragma unroll
      for (int ni = 0; ni < 4; ni++) {
        float p = __expf(s[ni][r] - mnew);
        s[ni][r] = p;
        rs += p;
      }
#pragma unroll
      for (int off = 1; off < 16; off <<= 1) rs += __shfl_xor(rs, off);
      l_run[r] = l_run[r] * corr + rs;
      m_run[r] = mnew;
#pragma unroll
      for (int di = 0; di < 4; di++) oacc[di][r] *= corr;
    }
    // P -> LDS (wave-private buffer; no barrier needed before reading back)
#pragma unroll
    for (int ni = 0; ni < 4; ni++)
#pragma unroll
      for (int r = 0; r < 4; r++)
        Ps[w][kg * 4 + r][ni * 16 + fr] = f2bf(s[ni][r]);
    // PV
    bf16x8 ap0 = *(const bf16x8*)&Ps[w][fr][kg * 8];
    bf16x8 ap1 = *(const bf16x8*)&Ps[w][fr][32 + kg * 8];
#pragma unroll
    for (int di = 0; di < 4; di++) {
      bf16x8 v0 = *(const bf16x8*)&VTs[di * 16 + fr][kg * 8];
      bf16x8 v1 = *(const bf16x8*)&VTs[di * 16 + fr][32 + kg * 8];
      oacc[di] = __builtin_amdgcn_mfma_f32_16x16x32_bf16(ap0, v0, oacc[di], 0, 0, 0);
      oacc[di] = __builtin_amdgcn_mfma_f32_16x16x32_bf16(ap1, v1, oacc[di], 0, 0, 0);
    }
    __syncthreads();
  }

  // epilogue: O[b][l][h*64+dh] bf16
  const int b = bh >> 4, h = bh & 15;
#pragma unroll
  for (int di = 0; di < 4; di++)
#pragma unroll
    for (int r = 0; r < 4; r++) {
      const int qg = q0 + w * 16 + kg * 4 + r;
      const int dh = di * 16 + fr;
      const float val = oacc[di][r] / l_run[r];
      O[((size_t)(b * LL + qg) * DM) + h * DH + dh] = f2bf(val);
    }
}

// ---------------------------------------------------------------------------
extern "C" void kernel_launch(void* const* d_in, const int* in_sizes, int n_in,
                              void* d_out, int out_size, void* d_ws, size_t ws_size,
                              hipStream_t stream) {
  (void)in_sizes; (void)n_in; (void)out_size; (void)ws_size;
  const float* q  = (const float*)d_in[0];
  const float* k  = (const float*)d_in[1];
  const float* v  = (const float*)d_in[2];
  const float* Wq = (const float*)d_in[3];
  const float* bq = (const float*)d_in[4];
  const float* Wk = (const float*)d_in[5];
  const float* bk = (const float*)d_in[6];
  const float* Wv = (const float*)d_in[7];
  const float* bv = (const float*)d_in[8];
  const float* Wo = (const float*)d_in[9];
  const float* bo = (const float*)d_in[10];

  char* ws = (char*)d_ws;
  const size_t WSZ = (size_t)DM * DM * 2;          // 2 MB per transposed weight
  const size_t HSZ = (size_t)MROWS * DM * 2;       // 16 MB per bf16 activation
  unsigned short* WqT = (unsigned short*)(ws);
  unsigned short* WkT = (unsigned short*)(ws + WSZ);
  unsigned short* WvT = (unsigned short*)(ws + 2 * WSZ);
  unsigned short* WoT = (unsigned short*)(ws + 3 * WSZ);
  unsigned short* Qh  = (unsigned short*)(ws + 4 * WSZ);
  unsigned short* Kh  = (unsigned short*)(ws + 4 * WSZ + HSZ);
  unsigned short* VhT = (unsigned short*)(ws + 4 * WSZ + 2 * HSZ);
  unsigned short* Oc  = (unsigned short*)(ws + 4 * WSZ + 3 * HSZ);

  dim3 tgrid(32, 32);
  transpose_w_kernel<<<tgrid, 256, 0, stream>>>(Wq, WqT);
  transpose_w_kernel<<<tgrid, 256, 0, stream>>>(Wk, WkT);
  transpose_w_kernel<<<tgrid, 256, 0, stream>>>(Wv, WvT);
  transpose_w_kernel<<<tgrid, 256, 0, stream>>>(Wo, WoT);

  qk_gemm_kernel<<<dim3(DM / 128, MROWS / 128, 2), 256, 0, stream>>>(
      q, k, WqT, WkT, bq, bk, Qh, Kh);
  v_gemm_kernel<<<dim3(DM / 128, MROWS / 128), 256, 0, stream>>>(
      v, WvT, bv, VhT);

  attn_kernel<<<dim3(LL / 64, BB * HEADS), 256, 0, stream>>>(Qh, Kh, VhT, Oc);

  oproj_gemm_kernel<<<dim3(DM / 128, MROWS / 128), 256, 0, stream>>>(
      Oc, WoT, bo, (float*)d_out);
}

// Round 4
// 355.002 us; speedup vs baseline: 1.3726x; 1.1442x over previous
//
#include <hip/hip_runtime.h>

#define DM 1024
#define HEADS 16
#define DH 64
#define BB 4
#define LL 2048
#define MROWS (BB * LL) /* 8192 */

typedef __bf16 bf16x8 __attribute__((ext_vector_type(8)));
typedef float f32x4 __attribute__((ext_vector_type(4)));
typedef float f32x16 __attribute__((ext_vector_type(16)));

__device__ __forceinline__ unsigned short f2bf(float f) {
  union { float f; unsigned int u; } v;
  v.f = f;
  unsigned int u = v.u;
  u += 0x7FFFu + ((u >> 16) & 1u);
  return (unsigned short)(u >> 16);
}
__device__ __forceinline__ unsigned int pack2(float a, float b) {
  return (unsigned int)f2bf(a) | ((unsigned int)f2bf(b) << 16);
}

// ---------------------------------------------------------------------------
// Weight transpose + bf16 convert: WT[n][k] = bf16(W[k][n]), 1024x1024
// ---------------------------------------------------------------------------
__global__ __launch_bounds__(256) void transpose_w_kernel(
    const float* __restrict__ W, unsigned short* __restrict__ WT) {
  __shared__ float tile[32][33];
  const int tx = threadIdx.x & 31;
  const int ty = threadIdx.x >> 5;
  const int x0 = blockIdx.x * 32;
  const int y0 = blockIdx.y * 32;
#pragma unroll
  for (int i = 0; i < 32; i += 8)
    tile[ty + i][tx] = W[(size_t)(y0 + ty + i) * DM + x0 + tx];
  __syncthreads();
#pragma unroll
  for (int i = 0; i < 32; i += 8)
    WT[(size_t)(x0 + ty + i) * DM + y0 + tx] = f2bf(tile[tx][ty + i]);
}

// ---------------------------------------------------------------------------
// GEMM: C = A(8192xK) * BT^T + bias.  A fp32 (AMODE 0) or bf16 (AMODE 1).
// OUTMODE 0: bf16 out scaled, head layout [B,H,L,DH].
// OUTMODE 1: fp32 row-major.
// OUTMODE 2: bf16 out, TRANSPOSED head layout [B,H,DH,L]  (for V)
// ---------------------------------------------------------------------------
template <int AMODE, int OUTMODE>
__device__ __forceinline__ void gemm_body(
    const void* __restrict__ Aptr, const unsigned short* __restrict__ BT,
    const float* __restrict__ bias, void* __restrict__ Cptr,
    int m0, int n0, float scale) {
  constexpr int K = DM, N = DM;
  __shared__ unsigned short As[128][40];
  __shared__ unsigned short Bs[128][40];
  const int t = threadIdx.x;
  const int lane = t & 63;
  const int w = t >> 6;
  const int wr = w >> 1, wc = w & 1;
  const int fr = lane & 15, kg = lane >> 4;

  const int c0 = t, c1 = t + 256;
  const int row0 = c0 >> 2, kc0 = (c0 & 3) * 8;
  const int row1 = c1 >> 2, kc1 = (c1 & 3) * 8;

  f32x4 acc[4][4] = {};

  for (int kt = 0; kt < K / 32; ++kt) {
    const int k0 = kt * 32;
    if (AMODE == 0) {
      const float* A = (const float*)Aptr;
      {
        const float* src = A + (size_t)(m0 + row0) * K + k0 + kc0;
        float4 x = *(const float4*)src;
        float4 y = *(const float4*)(src + 4);
        uint4 p = {pack2(x.x, x.y), pack2(x.z, x.w), pack2(y.x, y.y), pack2(y.z, y.w)};
        *(uint4*)&As[row0][kc0] = p;
      }
      {
        const float* src = A + (size_t)(m0 + row1) * K + k0 + kc1;
        float4 x = *(const float4*)src;
        float4 y = *(const float4*)(src + 4);
        uint4 p = {pack2(x.x, x.y), pack2(x.z, x.w), pack2(y.x, y.y), pack2(y.z, y.w)};
        *(uint4*)&As[row1][kc1] = p;
      }
    } else {
      const unsigned short* A = (const unsigned short*)Aptr;
      *(uint4*)&As[row0][kc0] = *(const uint4*)(A + (size_t)(m0 + row0) * K + k0 + kc0);
      *(uint4*)&As[row1][kc1] = *(const uint4*)(A + (size_t)(m0 + row1) * K + k0 + kc1);
    }
    *(uint4*)&Bs[row0][kc0] = *(const uint4*)(BT + (size_t)(n0 + row0) * K + k0 + kc0);
    *(uint4*)&Bs[row1][kc1] = *(const uint4*)(BT + (size_t)(n0 + row1) * K + k0 + kc1);
    __syncthreads();

    bf16x8 af[4], bfr[4];
#pragma unroll
    for (int i = 0; i < 4; i++)
      af[i] = *(const bf16x8*)&As[wr * 64 + i * 16 + fr][kg * 8];
#pragma unroll
    for (int i = 0; i < 4; i++)
      bfr[i] = *(const bf16x8*)&Bs[wc * 64 + i * 16 + fr][kg * 8];
#pragma unroll
    for (int i = 0; i < 4; i++)
#pragma unroll
      for (int j = 0; j < 4; j++)
        acc[i][j] = __builtin_amdgcn_mfma_f32_16x16x32_bf16(af[i], bfr[j], acc[i][j], 0, 0, 0);
    __syncthreads();
  }

#pragma unroll
  for (int j = 0; j < 4; j++) {
    const int gcol = n0 + wc * 64 + j * 16 + fr;
    const float bv = bias[gcol];
    const int h = gcol >> 6, dh = gcol & 63;
#pragma unroll
    for (int i = 0; i < 4; i++) {
      const int grow0 = m0 + wr * 64 + i * 16 + kg * 4;
      if (OUTMODE == 2) {
        const int b = grow0 >> 11, l = grow0 & 2047;
        uint2 pk;
        pk.x = pack2(acc[i][j][0] + bv, acc[i][j][1] + bv);
        pk.y = pack2(acc[i][j][2] + bv, acc[i][j][3] + bv);
        *(uint2*)((unsigned short*)Cptr +
                  ((size_t)((b * HEADS + h) * DH + dh)) * LL + l) = pk;
      } else {
#pragma unroll
        for (int r = 0; r < 4; r++) {
          const int grow = grow0 + r;
          if (OUTMODE == 0) {
            const float val = (acc[i][j][r] + bv) * scale;
            const int b = grow >> 11, l = grow & 2047;
            ((unsigned short*)Cptr)[(((size_t)(b * HEADS + h) * LL + l) << 6) + dh] = f2bf(val);
          } else {
            ((float*)Cptr)[(size_t)grow * N + gcol] = acc[i][j][r] + bv;
          }
        }
      }
    }
  }
}

// scale = 0.125 * log2(e) folded into Q so attention softmax can use exp2
#define QSCALE 0.18033688011112042f

__global__ __launch_bounds__(256) void qk_gemm_kernel(
    const float* __restrict__ q, const float* __restrict__ k,
    const unsigned short* __restrict__ WqT, const unsigned short* __restrict__ WkT,
    const float* __restrict__ bq, const float* __restrict__ bk,
    unsigned short* __restrict__ Qh, unsigned short* __restrict__ Kh) {
  const int z = blockIdx.z;
  const float* A = z ? k : q;
  const unsigned short* BT = z ? WkT : WqT;
  const float* bias = z ? bk : bq;
  unsigned short* C = z ? Kh : Qh;
  gemm_body<0, 0>(A, BT, bias, C, blockIdx.y * 128, blockIdx.x * 128,
                  z ? 1.0f : QSCALE);
}

__global__ __launch_bounds__(256) void v_gemm_kernel(
    const float* __restrict__ v, const unsigned short* __restrict__ WvT,
    const float* __restrict__ bv, unsigned short* __restrict__ VhT) {
  gemm_body<0, 2>(v, WvT, bv, VhT, blockIdx.y * 128, blockIdx.x * 128, 1.0f);
}

__global__ __launch_bounds__(256) void oproj_gemm_kernel(
    const unsigned short* __restrict__ Oc, const unsigned short* __restrict__ WoT,
    const float* __restrict__ bo, float* __restrict__ out) {
  gemm_body<1, 1>(Oc, WoT, bo, out, blockIdx.y * 128, blockIdx.x * 128, 1.0f);
}

// ---------------------------------------------------------------------------
// Causal flash attention, swapped-operand 32x32x16 form.
// Grid (qtile=16, bh=64).  Block 256 = 4 waves; each wave owns 32 q-rows
// (q = q0 + w*32 + (lane&31)); KV tiles of 64; Dh = 64.
// S^T = mfma(K, Q): D[kv][q] -> each lane holds 32 kv values of ONE q row
//   (rows (reg&3)+8*(reg>>2)+4*hi per 32-tile; col = lane&31 = q).
// Softmax fully in-register: in-lane tree + one shfl_xor(32).
// PV: O^T = mfma(VT, P): D[dh][q] -> corr/l stay lane-local.
// P fragments built in-register: 16 pack2 + 16 shfl_xor(32) per tile.
// LDS row stride 78 (39 words, odd) -> conflict-free b128 reads.
// ---------------------------------------------------------------------------
#define PAD 78
__global__ __launch_bounds__(256) void attn_kernel(
    const unsigned short* __restrict__ Qh, const unsigned short* __restrict__ Kh,
    const unsigned short* __restrict__ VhT, unsigned short* __restrict__ O) {
  __shared__ unsigned short Ks[64][PAD];
  __shared__ unsigned short VTs[64][PAD];  // [dh][kv]
  const int t = threadIdx.x, lane = t & 63, w = t >> 6;
  const int lo5 = lane & 31, hi = lane >> 5;
  const int bh = blockIdx.y;
  const int qi = (int)gridDim.x - 1 - (int)blockIdx.x;  // longest-first
  const int q0 = qi * 128;
  const size_t base = (size_t)bh * LL * DH;
  const int qrow = q0 + w * 32 + lo5;  // this lane's q row

  // Q fragments: B-operand, col = q = lane&31, k = kc*16 + hi*8 + j
  bf16x8 qf[4];
  {
    const unsigned short* Qb = Qh + base + (size_t)qrow * DH + hi * 8;
#pragma unroll
    for (int kc = 0; kc < 4; kc++) qf[kc] = *(const bf16x8*)(Qb + kc * 16);
  }

  float m_run = -INFINITY, l_run = 0.f;
  f32x16 oacc[2] = {};  // D[dh][q], od in {0,1}

  // staging decomposition for a [64][64] bf16 tile: 512 chunks of 8 elems
  const int rA = t >> 3, kA = (t & 7) * 8;
  const int rB = rA + 32;
  const unsigned short* Kb = Kh + base;
  const unsigned short* Vb = VhT + base;  // [dh][l]

  // prefetch tile 0 into registers
  uint4 kra = *(const uint4*)(Kb + (size_t)rA * DH + kA);
  uint4 krb = *(const uint4*)(Kb + (size_t)rB * DH + kA);
  uint4 vra = *(const uint4*)(Vb + (size_t)rA * LL + kA);
  uint4 vrb = *(const uint4*)(Vb + (size_t)rB * LL + kA);

  const int ntiles = 2 * (qi + 1);
  for (int jt = 0; jt < ntiles; ++jt) {
    *(uint4*)&Ks[rA][kA] = kra;
    *(uint4*)&Ks[rB][kA] = krb;
    *(uint4*)&VTs[rA][kA] = vra;
    *(uint4*)&VTs[rB][kA] = vrb;
    __syncthreads();

    if (jt + 1 < ntiles) {
      const int kv1 = (jt + 1) * 64;
      kra = *(const uint4*)(Kb + (size_t)(kv1 + rA) * DH + kA);
      krb = *(const uint4*)(Kb + (size_t)(kv1 + rB) * DH + kA);
      vra = *(const uint4*)(Vb + (size_t)rA * LL + kv1 + kA);
      vrb = *(const uint4*)(Vb + (size_t)rB * LL + kv1 + kA);
    }

    // S^T = K * Q^T : two 32x32 tiles along kv, K-dim = Dh = 64
    f32x16 s[2] = {};
#pragma unroll
    for (int tt = 0; tt < 2; tt++)
#pragma unroll
      for (int kc = 0; kc < 4; kc++) {
        bf16x8 kf = *(const bf16x8*)&Ks[tt * 32 + lo5][kc * 16 + hi * 8];
        s[tt] = __builtin_amdgcn_mfma_f32_32x32x16_bf16(kf, qf[kc], s[tt], 0, 0, 0);
      }

    // causal mask (only tiles overlapping the diagonal of this wave)
    const int kv0 = jt * 64;
    if (kv0 + 63 > q0 + w * 32) {
      const int thr = qrow - kv0 - 4 * hi;  // mask where tt*32+(i&3)+8*(i>>2) > thr
#pragma unroll
      for (int tt = 0; tt < 2; tt++)
#pragma unroll
        for (int i = 0; i < 16; i++) {
          const int kvoff = tt * 32 + (i & 3) + 8 * (i >> 2);
          s[tt][i] = (kvoff > thr) ? -1e30f : s[tt][i];
        }
    }

    // row max: in-lane tree over 32 + partner half
    float mx;
    {
      float m8[8];
#pragma unroll
      for (int i = 0; i < 8; i++)
        m8[i] = fmaxf(fmaxf(s[0][i], s[0][i + 8]), fmaxf(s[1][i], s[1][i + 8]));
#pragma unroll
      for (int st = 4; st > 0; st >>= 1)
#pragma unroll
        for (int i = 0; i < st; i++) m8[i] = fmaxf(m8[i], m8[i + st]);
      mx = m8[0];
    }
    mx = fmaxf(mx, __shfl_xor(mx, 32));
    const float mnew = fmaxf(m_run, mx);
    const float corr = exp2f(m_run - mnew);
    m_run = mnew;

    // p = exp2(s - m)   (logits pre-scaled by log2e at the Q projection)
#pragma unroll
    for (int tt = 0; tt < 2; tt++)
#pragma unroll
      for (int i = 0; i < 16; i++) s[tt][i] = exp2f(s[tt][i] - mnew);

    // row sum: in-lane tree + partner half
    float rs;
    {
      float a8[8];
#pragma unroll
      for (int i = 0; i < 8; i++)
        a8[i] = (s[0][i] + s[0][i + 8]) + (s[1][i] + s[1][i + 8]);
#pragma unroll
      for (int st = 4; st > 0; st >>= 1)
#pragma unroll
        for (int i = 0; i < st; i++) a8[i] += a8[i + st];
      rs = a8[0];
    }
    rs += __shfl_xor(rs, 32);
    l_run = l_run * corr + rs;
#pragma unroll
    for (int od = 0; od < 2; od++)
#pragma unroll
      for (int i = 0; i < 16; i++) oacc[od][i] *= corr;

    // build P B-operand fragments: pa[ks] holds kv = ks*16 + hi*8 + j
    union U8 { uint4 u; bf16x8 v; } pa[4];
#pragma unroll
    for (int ks = 0; ks < 4; ks++) {
      const int tt = ks >> 1, b0 = (ks & 1) * 8;
      const unsigned int w0 = pack2(s[tt][b0 + 0], s[tt][b0 + 1]);
      const unsigned int w1 = pack2(s[tt][b0 + 2], s[tt][b0 + 3]);
      const unsigned int w2 = pack2(s[tt][b0 + 4], s[tt][b0 + 5]);
      const unsigned int w3 = pack2(s[tt][b0 + 6], s[tt][b0 + 7]);
      const unsigned int p0 = (unsigned int)__shfl_xor((int)w0, 32);
      const unsigned int p1 = (unsigned int)__shfl_xor((int)w1, 32);
      const unsigned int p2 = (unsigned int)__shfl_xor((int)w2, 32);
      const unsigned int p3 = (unsigned int)__shfl_xor((int)w3, 32);
      pa[ks].u = hi ? make_uint4(p2, p3, w2, w3) : make_uint4(w0, w1, p0, p1);
    }

    // O^T += VT * P : D[dh][q]
#pragma unroll
    for (int od = 0; od < 2; od++)
#pragma unroll
      for (int ks = 0; ks < 4; ks++) {
        bf16x8 vf = *(const bf16x8*)&VTs[od * 32 + lo5][ks * 16 + hi * 8];
        oacc[od] = __builtin_amdgcn_mfma_f32_32x32x16_bf16(vf, pa[ks].v, oacc[od], 0, 0, 0);
      }
    __syncthreads();
  }

  // epilogue: O[b][l][h*64+dh] bf16; lane's q = qrow, dh = crow(reg,hi)+od*32
  const float linv = 1.f / l_run;
  const int b = bh >> 4, h = bh & 15;
  unsigned short* Ob = O + ((size_t)(b * LL + qrow) * DM) + h * DH;
#pragma unroll
  for (int od = 0; od < 2; od++)
#pragma unroll
    for (int m = 0; m < 8; m++) {
      const int dh0 = od * 32 + ((2 * m) & 3) + 8 * ((2 * m) >> 2) + 4 * hi;
      const unsigned int pk =
          pack2(oacc[od][2 * m] * linv, oacc[od][2 * m + 1] * linv);
      *(unsigned int*)(Ob + dh0) = pk;
    }
}

// ---------------------------------------------------------------------------
extern "C" void kernel_launch(void* const* d_in, const int* in_sizes, int n_in,
                              void* d_out, int out_size, void* d_ws, size_t ws_size,
                              hipStream_t stream) {
  (void)in_sizes; (void)n_in; (void)out_size; (void)ws_size;
  const float* q  = (const float*)d_in[0];
  const float* k  = (const float*)d_in[1];
  const float* v  = (const float*)d_in[2];
  const float* Wq = (const float*)d_in[3];
  const float* bq = (const float*)d_in[4];
  const float* Wk = (const float*)d_in[5];
  const float* bk = (const float*)d_in[6];
  const float* Wv = (const float*)d_in[7];
  const float* bv = (const float*)d_in[8];
  const float* Wo = (const float*)d_in[9];
  const float* bo = (const float*)d_in[10];

  char* ws = (char*)d_ws;
  const size_t WSZ = (size_t)DM * DM * 2;          // 2 MB per transposed weight
  const size_t HSZ = (size_t)MROWS * DM * 2;       // 16 MB per bf16 activation
  unsigned short* WqT = (unsigned short*)(ws);
  unsigned short* WkT = (unsigned short*)(ws + WSZ);
  unsigned short* WvT = (unsigned short*)(ws + 2 * WSZ);
  unsigned short* WoT = (unsigned short*)(ws + 3 * WSZ);
  unsigned short* Qh  = (unsigned short*)(ws + 4 * WSZ);
  unsigned short* Kh  = (unsigned short*)(ws + 4 * WSZ + HSZ);
  unsigned short* VhT = (unsigned short*)(ws + 4 * WSZ + 2 * HSZ);
  unsigned short* Oc  = (unsigned short*)(ws + 4 * WSZ + 3 * HSZ);

  dim3 tgrid(32, 32);
  transpose_w_kernel<<<tgrid, 256, 0, stream>>>(Wq, WqT);
  transpose_w_kernel<<<tgrid, 256, 0, stream>>>(Wk, WkT);
  transpose_w_kernel<<<tgrid, 256, 0, stream>>>(Wv, WvT);
  transpose_w_kernel<<<tgrid, 256, 0, stream>>>(Wo, WoT);

  qk_gemm_kernel<<<dim3(DM / 128, MROWS / 128, 2), 256, 0, stream>>>(
      q, k, WqT, WkT, bq, bk, Qh, Kh);
  v_gemm_kernel<<<dim3(DM / 128, MROWS / 128), 256, 0, stream>>>(
      v, WvT, bv, VhT);

  attn_kernel<<<dim3(LL / 128, BB * HEADS), 256, 0, stream>>>(Qh, Kh, VhT, Oc);

  oproj_gemm_kernel<<<dim3(DM / 128, MROWS / 128), 256, 0, stream>>>(
      Oc, WoT, bo, (float*)d_out);
}

// Round 5
// 295.459 us; speedup vs baseline: 1.6492x; 1.2015x over previous
//
#include <hip/hip_runtime.h>

#define DM 1024
#define HEADS 16
#define DH 64
#define BB 4
#define LL 2048
#define MROWS (BB * LL) /* 8192 */

typedef __bf16 bf16x8 __attribute__((ext_vector_type(8)));
typedef float f32x4 __attribute__((ext_vector_type(4)));
typedef float f32x16 __attribute__((ext_vector_type(16)));

// HW round-to-nearest-even f32->bf16 via compiler (emits v_cvt_pk_bf16_f32)
__device__ __forceinline__ unsigned short f2bf(float f) {
  __bf16 h = (__bf16)f;
  return __builtin_bit_cast(unsigned short, h);
}
__device__ __forceinline__ unsigned int pack2(float a, float b) {
  return (unsigned int)f2bf(a) | ((unsigned int)f2bf(b) << 16);
}

// ---------------------------------------------------------------------------
// Weight transpose + bf16 convert: WT[n][k] = bf16(W[k][n]), 1024x1024, z=4
// ---------------------------------------------------------------------------
__global__ __launch_bounds__(256) void transpose_w_kernel(
    const float* __restrict__ W0, const float* __restrict__ W1,
    const float* __restrict__ W2, const float* __restrict__ W3,
    unsigned short* __restrict__ T0, unsigned short* __restrict__ T1,
    unsigned short* __restrict__ T2, unsigned short* __restrict__ T3) {
  const float* Wt[4] = {W0, W1, W2, W3};
  unsigned short* Tt[4] = {T0, T1, T2, T3};
  const float* W = Wt[blockIdx.z];
  unsigned short* WT = Tt[blockIdx.z];
  __shared__ float tile[32][33];
  const int tx = threadIdx.x & 31;
  const int ty = threadIdx.x >> 5;
  const int x0 = blockIdx.x * 32;
  const int y0 = blockIdx.y * 32;
#pragma unroll
  for (int i = 0; i < 32; i += 8)
    tile[ty + i][tx] = W[(size_t)(y0 + ty + i) * DM + x0 + tx];
  __syncthreads();
#pragma unroll
  for (int i = 0; i < 32; i += 8)
    WT[(size_t)(x0 + ty + i) * DM + y0 + tx] = f2bf(tile[tx][ty + i]);
}

// ---------------------------------------------------------------------------
// GEMM: C = A(8192xK) * BT^T + bias.  A fp32 (AMODE 0) or bf16 (AMODE 1).
// OUTMODE 0: bf16 out scaled, head layout [B,H,L,DH].
// OUTMODE 1: fp32 row-major.
// OUTMODE 2: bf16 out, TRANSPOSED head layout [B,H,DH,L]  (for V)
// ---------------------------------------------------------------------------
template <int AMODE, int OUTMODE>
__device__ __forceinline__ void gemm_body(
    const void* __restrict__ Aptr, const unsigned short* __restrict__ BT,
    const float* __restrict__ bias, void* __restrict__ Cptr,
    int m0, int n0, float scale) {
  constexpr int K = DM, N = DM;
  __shared__ unsigned short As[128][40];
  __shared__ unsigned short Bs[128][40];
  const int t = threadIdx.x;
  const int lane = t & 63;
  const int w = t >> 6;
  const int wr = w >> 1, wc = w & 1;
  const int fr = lane & 15, kg = lane >> 4;

  const int c0 = t, c1 = t + 256;
  const int row0 = c0 >> 2, kc0 = (c0 & 3) * 8;
  const int row1 = c1 >> 2, kc1 = (c1 & 3) * 8;

  f32x4 acc[4][4] = {};

  for (int kt = 0; kt < K / 32; ++kt) {
    const int k0 = kt * 32;
    if (AMODE == 0) {
      const float* A = (const float*)Aptr;
      {
        const float* src = A + (size_t)(m0 + row0) * K + k0 + kc0;
        float4 x = *(const float4*)src;
        float4 y = *(const float4*)(src + 4);
        uint4 p = {pack2(x.x, x.y), pack2(x.z, x.w), pack2(y.x, y.y), pack2(y.z, y.w)};
        *(uint4*)&As[row0][kc0] = p;
      }
      {
        const float* src = A + (size_t)(m0 + row1) * K + k0 + kc1;
        float4 x = *(const float4*)src;
        float4 y = *(const float4*)(src + 4);
        uint4 p = {pack2(x.x, x.y), pack2(x.z, x.w), pack2(y.x, y.y), pack2(y.z, y.w)};
        *(uint4*)&As[row1][kc1] = p;
      }
    } else {
      const unsigned short* A = (const unsigned short*)Aptr;
      *(uint4*)&As[row0][kc0] = *(const uint4*)(A + (size_t)(m0 + row0) * K + k0 + kc0);
      *(uint4*)&As[row1][kc1] = *(const uint4*)(A + (size_t)(m0 + row1) * K + k0 + kc1);
    }
    *(uint4*)&Bs[row0][kc0] = *(const uint4*)(BT + (size_t)(n0 + row0) * K + k0 + kc0);
    *(uint4*)&Bs[row1][kc1] = *(const uint4*)(BT + (size_t)(n0 + row1) * K + k0 + kc1);
    __syncthreads();

    bf16x8 af[4], bfr[4];
#pragma unroll
    for (int i = 0; i < 4; i++)
      af[i] = *(const bf16x8*)&As[wr * 64 + i * 16 + fr][kg * 8];
#pragma unroll
    for (int i = 0; i < 4; i++)
      bfr[i] = *(const bf16x8*)&Bs[wc * 64 + i * 16 + fr][kg * 8];
#pragma unroll
    for (int i = 0; i < 4; i++)
#pragma unroll
      for (int j = 0; j < 4; j++)
        acc[i][j] = __builtin_amdgcn_mfma_f32_16x16x32_bf16(af[i], bfr[j], acc[i][j], 0, 0, 0);
    __syncthreads();
  }

#pragma unroll
  for (int j = 0; j < 4; j++) {
    const int gcol = n0 + wc * 64 + j * 16 + fr;
    const float bv = bias[gcol];
    const int h = gcol >> 6, dh = gcol & 63;
#pragma unroll
    for (int i = 0; i < 4; i++) {
      const int grow0 = m0 + wr * 64 + i * 16 + kg * 4;
      if (OUTMODE == 2) {
        const int b = grow0 >> 11, l = grow0 & 2047;
        uint2 pk;
        pk.x = pack2(acc[i][j][0] + bv, acc[i][j][1] + bv);
        pk.y = pack2(acc[i][j][2] + bv, acc[i][j][3] + bv);
        *(uint2*)((unsigned short*)Cptr +
                  ((size_t)((b * HEADS + h) * DH + dh)) * LL + l) = pk;
      } else {
#pragma unroll
        for (int r = 0; r < 4; r++) {
          const int grow = grow0 + r;
          if (OUTMODE == 0) {
            const float val = (acc[i][j][r] + bv) * scale;
            const int b = grow >> 11, l = grow & 2047;
            ((unsigned short*)Cptr)[(((size_t)(b * HEADS + h) * LL + l) << 6) + dh] = f2bf(val);
          } else {
            ((float*)Cptr)[(size_t)grow * N + gcol] = acc[i][j][r] + bv;
          }
        }
      }
    }
  }
}

// scale = 0.125 * log2(e) folded into Q so attention softmax can use exp2
#define QSCALE 0.18033688011112042f

__global__ __launch_bounds__(256) void qk_gemm_kernel(
    const float* __restrict__ q, const float* __restrict__ k,
    const unsigned short* __restrict__ WqT, const unsigned short* __restrict__ WkT,
    const float* __restrict__ bq, const float* __restrict__ bk,
    unsigned short* __restrict__ Qh, unsigned short* __restrict__ Kh) {
  const int z = blockIdx.z;
  const float* A = z ? k : q;
  const unsigned short* BT = z ? WkT : WqT;
  const float* bias = z ? bk : bq;
  unsigned short* C = z ? Kh : Qh;
  gemm_body<0, 0>(A, BT, bias, C, blockIdx.y * 128, blockIdx.x * 128,
                  z ? 1.0f : QSCALE);
}

__global__ __launch_bounds__(256) void v_gemm_kernel(
    const float* __restrict__ v, const unsigned short* __restrict__ WvT,
    const float* __restrict__ bv, unsigned short* __restrict__ VhT) {
  gemm_body<0, 2>(v, WvT, bv, VhT, blockIdx.y * 128, blockIdx.x * 128, 1.0f);
}

__global__ __launch_bounds__(256) void oproj_gemm_kernel(
    const unsigned short* __restrict__ Oc, const unsigned short* __restrict__ WoT,
    const float* __restrict__ bo, float* __restrict__ out) {
  gemm_body<1, 1>(Oc, WoT, bo, out, blockIdx.y * 128, blockIdx.x * 128, 1.0f);
}

// ---------------------------------------------------------------------------
// Causal flash attention, swapped-operand 32x32x16, 8-wave blocks.
// Grid (qtile=8, bh=64).  Block 512 = 8 waves; each wave owns 32 q-rows
// (q = q0 + w*32 + (lane&31)); KV tiles of 64; Dh = 64.
// Double-buffered K/V LDS, 1 barrier/iter; next tile prefetched into regs
// before the barrier (load latency hides under compute).
// Waves skip compute (not barriers/staging) on tiles past their diagonal.
// Defer-max: skip O-rescale when no row's max grew by >8 (log2 domain).
// LDS row stride 78 (odd word count) -> conflict-free b128 reads.
// ---------------------------------------------------------------------------
#define PAD 78
__global__ __launch_bounds__(512) void attn_kernel(
    const unsigned short* __restrict__ Qh, const unsigned short* __restrict__ Kh,
    const unsigned short* __restrict__ VhT, unsigned short* __restrict__ O) {
  __shared__ unsigned short Ks[2][64][PAD];
  __shared__ unsigned short VTs[2][64][PAD];  // [dh][kv]
  const int t = threadIdx.x, lane = t & 63, w = t >> 6;  // w in 0..7
  const int lo5 = lane & 31, hi = lane >> 5;
  const int bh = blockIdx.y;
  const int qi = (int)gridDim.x - 1 - (int)blockIdx.x;  // longest-first
  const int q0 = qi * 256;
  const size_t base = (size_t)bh * LL * DH;
  const int qrow = q0 + w * 32 + lo5;  // this lane's q row

  // Q fragments: B-operand, col = q = lane&31, k = kc*16 + hi*8 + j
  bf16x8 qf[4];
  {
    const unsigned short* Qb = Qh + base + (size_t)qrow * DH + hi * 8;
#pragma unroll
    for (int kc = 0; kc < 4; kc++) qf[kc] = *(const bf16x8*)(Qb + kc * 16);
  }

  float m_run = -INFINITY, l_run = 0.f;
  f32x16 oacc[2] = {};  // D[dh][q]

  // staging: [64][64] bf16 tile, 512 threads x one 8-elem chunk each
  const int rA = t >> 3, kA = (t & 7) * 8;
  const unsigned short* Kb = Kh + base;
  const unsigned short* Vb = VhT + base;  // [dh][l]

  const int ntiles = 4 * (qi + 1);
  const int my_last = (q0 + w * 32 + 31) >> 6;  // last tile this wave needs

  // prologue: tile 0 -> regs -> buf0
  uint4 kr = *(const uint4*)(Kb + (size_t)rA * DH + kA);
  uint4 vr = *(const uint4*)(Vb + (size_t)rA * LL + kA);
  *(uint4*)&Ks[0][rA][kA] = kr;
  *(uint4*)&VTs[0][rA][kA] = vr;

  for (int jt = 0; jt < ntiles; ++jt) {
    const int cur = jt & 1;
    // issue next tile's global loads (consumed after compute)
    if (jt + 1 < ntiles) {
      const int kv1 = (jt + 1) * 64;
      kr = *(const uint4*)(Kb + (size_t)(kv1 + rA) * DH + kA);
      vr = *(const uint4*)(Vb + (size_t)rA * LL + kv1 + kA);
    }
    __syncthreads();  // buf[cur] writes from prev iter visible

    if (jt <= my_last) {
      // S^T = K * Q^T : two 32x32 tiles along kv, K-dim = Dh = 64
      f32x16 s2[2] = {};
      __builtin_amdgcn_s_setprio(1);
#pragma unroll
      for (int tt = 0; tt < 2; tt++)
#pragma unroll
        for (int kc = 0; kc < 4; kc++) {
          bf16x8 kf = *(const bf16x8*)&Ks[cur][tt * 32 + lo5][kc * 16 + hi * 8];
          s2[tt] = __builtin_amdgcn_mfma_f32_32x32x16_bf16(kf, qf[kc], s2[tt], 0, 0, 0);
        }
      __builtin_amdgcn_s_setprio(0);

      // causal mask (only tiles overlapping this wave's diagonal)
      const int kv0 = jt * 64;
      if (kv0 + 63 > q0 + w * 32) {
        const int thr = qrow - kv0 - 4 * hi;
#pragma unroll
        for (int tt = 0; tt < 2; tt++)
#pragma unroll
          for (int i = 0; i < 16; i++) {
            const int kvoff = tt * 32 + (i & 3) + 8 * (i >> 2);
            s2[tt][i] = (kvoff > thr) ? -1e30f : s2[tt][i];
          }
      }

      // row max: in-lane tree + partner half
      float mx;
      {
        float m8[8];
#pragma unroll
        for (int i = 0; i < 8; i++)
          m8[i] = fmaxf(fmaxf(s2[0][i], s2[0][i + 8]), fmaxf(s2[1][i], s2[1][i + 8]));
#pragma unroll
        for (int st = 4; st > 0; st >>= 1)
#pragma unroll
          for (int i = 0; i < st; i++) m8[i] = fmaxf(m8[i], m8[i + st]);
        mx = m8[0];
      }
      mx = fmaxf(mx, __shfl_xor(mx, 32));

      // defer-max: only rescale when some row's max grew by >8 (2^8 P-bound)
      if (__any(mx > m_run + 8.0f)) {
        const float mnew = fmaxf(m_run, mx);
        const float corr = exp2f(m_run - mnew);
        m_run = mnew;
        l_run *= corr;
#pragma unroll
        for (int od = 0; od < 2; od++)
#pragma unroll
          for (int i = 0; i < 16; i++) oacc[od][i] *= corr;
      }

      // p = exp2(s - m)   (logits pre-scaled by log2e at the Q projection)
#pragma unroll
      for (int tt = 0; tt < 2; tt++)
#pragma unroll
        for (int i = 0; i < 16; i++) s2[tt][i] = exp2f(s2[tt][i] - m_run);

      // row sum: in-lane tree + partner half
      float rs;
      {
        float a8[8];
#pragma unroll
        for (int i = 0; i < 8; i++)
          a8[i] = (s2[0][i] + s2[0][i + 8]) + (s2[1][i] + s2[1][i + 8]);
#pragma unroll
        for (int st = 4; st > 0; st >>= 1)
#pragma unroll
          for (int i = 0; i < st; i++) a8[i] += a8[i + st];
        rs = a8[0];
      }
      rs += __shfl_xor(rs, 32);
      l_run += rs;

      // build P B-operand fragments: pa[ks] holds kv = ks*16 + hi*8 + j
      union U8 { uint4 u; bf16x8 v; } pa[4];
#pragma unroll
      for (int ks = 0; ks < 4; ks++) {
        const int tt = ks >> 1, b0 = (ks & 1) * 8;
        const unsigned int w0 = pack2(s2[tt][b0 + 0], s2[tt][b0 + 1]);
        const unsigned int w1 = pack2(s2[tt][b0 + 2], s2[tt][b0 + 3]);
        const unsigned int w2 = pack2(s2[tt][b0 + 4], s2[tt][b0 + 5]);
        const unsigned int w3 = pack2(s2[tt][b0 + 6], s2[tt][b0 + 7]);
        const unsigned int p0 = (unsigned int)__shfl_xor((int)w0, 32);
        const unsigned int p1 = (unsigned int)__shfl_xor((int)w1, 32);
        const unsigned int p2 = (unsigned int)__shfl_xor((int)w2, 32);
        const unsigned int p3 = (unsigned int)__shfl_xor((int)w3, 32);
        pa[ks].u = hi ? make_uint4(p2, p3, w2, w3) : make_uint4(w0, w1, p0, p1);
      }

      // O^T += VT * P : D[dh][q]
      __builtin_amdgcn_s_setprio(1);
#pragma unroll
      for (int od = 0; od < 2; od++)
#pragma unroll
        for (int ks = 0; ks < 4; ks++) {
          bf16x8 vf = *(const bf16x8*)&VTs[cur][od * 32 + lo5][ks * 16 + hi * 8];
          oacc[od] = __builtin_amdgcn_mfma_f32_32x32x16_bf16(vf, pa[ks].v, oacc[od], 0, 0, 0);
        }
      __builtin_amdgcn_s_setprio(0);
    }

    // stage next tile into the other buffer (visible after next barrier)
    if (jt + 1 < ntiles) {
      *(uint4*)&Ks[cur ^ 1][rA][kA] = kr;
      *(uint4*)&VTs[cur ^ 1][rA][kA] = vr;
    }
  }

  // epilogue: O[b][l][h*64+dh] bf16; lane's q = qrow, dh = crow(reg,hi)+od*32
  const float linv = 1.f / l_run;
  const int b = bh >> 4, h = bh & 15;
  unsigned short* Ob = O + ((size_t)(b * LL + qrow) * DM) + h * DH;
#pragma unroll
  for (int od = 0; od < 2; od++)
#pragma unroll
    for (int m = 0; m < 8; m++) {
      const int dh0 = od * 32 + ((2 * m) & 3) + 8 * ((2 * m) >> 2) + 4 * hi;
      const unsigned int pk =
          pack2(oacc[od][2 * m] * linv, oacc[od][2 * m + 1] * linv);
      *(unsigned int*)(Ob + dh0) = pk;
    }
}

// ---------------------------------------------------------------------------
extern "C" void kernel_launch(void* const* d_in, const int* in_sizes, int n_in,
                              void* d_out, int out_size, void* d_ws, size_t ws_size,
                              hipStream_t stream) {
  (void)in_sizes; (void)n_in; (void)out_size; (void)ws_size;
  const float* q  = (const float*)d_in[0];
  const float* k  = (const float*)d_in[1];
  const float* v  = (const float*)d_in[2];
  const float* Wq = (const float*)d_in[3];
  const float* bq = (const float*)d_in[4];
  const float* Wk = (const float*)d_in[5];
  const float* bk = (const float*)d_in[6];
  const float* Wv = (const float*)d_in[7];
  const float* bv = (const float*)d_in[8];
  const float* Wo = (const float*)d_in[9];
  const float* bo = (const float*)d_in[10];

  char* ws = (char*)d_ws;
  const size_t WSZ = (size_t)DM * DM * 2;          // 2 MB per transposed weight
  const size_t HSZ = (size_t)MROWS * DM * 2;       // 16 MB per bf16 activation
  unsigned short* WqT = (unsigned short*)(ws);
  unsigned short* WkT = (unsigned short*)(ws + WSZ);
  unsigned short* WvT = (unsigned short*)(ws + 2 * WSZ);
  unsigned short* WoT = (unsigned short*)(ws + 3 * WSZ);
  unsigned short* Qh  = (unsigned short*)(ws + 4 * WSZ);
  unsigned short* Kh  = (unsigned short*)(ws + 4 * WSZ + HSZ);
  unsigned short* VhT = (unsigned short*)(ws + 4 * WSZ + 2 * HSZ);
  unsigned short* Oc  = (unsigned short*)(ws + 4 * WSZ + 3 * HSZ);

  transpose_w_kernel<<<dim3(32, 32, 4), 256, 0, stream>>>(
      Wq, Wk, Wv, Wo, WqT, WkT, WvT, WoT);

  qk_gemm_kernel<<<dim3(DM / 128, MROWS / 128, 2), 256, 0, stream>>>(
      q, k, WqT, WkT, bq, bk, Qh, Kh);
  v_gemm_kernel<<<dim3(DM / 128, MROWS / 128), 256, 0, stream>>>(
      v, WvT, bv, VhT);

  attn_kernel<<<dim3(LL / 256, BB * HEADS), 512, 0, stream>>>(Qh, Kh, VhT, Oc);

  oproj_gemm_kernel<<<dim3(DM / 128, MROWS / 128), 256, 0, stream>>>(
      Oc, WoT, bo, (float*)d_out);
}

// Round 6
// 268.336 us; speedup vs baseline: 1.8160x; 1.1011x over previous
//
#include <hip/hip_runtime.h>

#define DM 1024
#define HEADS 16
#define DH 64
#define BB 4
#define LL 2048
#define MROWS (BB * LL) /* 8192 */

typedef __bf16 bf16x8 __attribute__((ext_vector_type(8)));
typedef float f32x4 __attribute__((ext_vector_type(4)));
typedef float f32x16 __attribute__((ext_vector_type(16)));

// HW round-to-nearest-even f32->bf16 via compiler (emits v_cvt_pk_bf16_f32)
__device__ __forceinline__ unsigned short f2bf(float f) {
  __bf16 h = (__bf16)f;
  return __builtin_bit_cast(unsigned short, h);
}
__device__ __forceinline__ unsigned int pack2(float a, float b) {
  return (unsigned int)f2bf(a) | ((unsigned int)f2bf(b) << 16);
}

// async global->LDS, 16B per lane; LDS dest is wave-uniform base + lane*16
__device__ __forceinline__ void gload16(const unsigned short* g, unsigned short* l) {
  __builtin_amdgcn_global_load_lds(
      (const __attribute__((address_space(1))) unsigned int*)(const void*)g,
      (__attribute__((address_space(3))) unsigned int*)(void*)l, 16, 0, 0);
}

// ---------------------------------------------------------------------------
// Weight transpose + bf16 convert: WT[n][k] = bf16(W[k][n]), 1024x1024, z=4
// ---------------------------------------------------------------------------
__global__ __launch_bounds__(256) void transpose_w_kernel(
    const float* __restrict__ W0, const float* __restrict__ W1,
    const float* __restrict__ W2, const float* __restrict__ W3,
    unsigned short* __restrict__ T0, unsigned short* __restrict__ T1,
    unsigned short* __restrict__ T2, unsigned short* __restrict__ T3) {
  const float* Wt[4] = {W0, W1, W2, W3};
  unsigned short* Tt[4] = {T0, T1, T2, T3};
  const float* W = Wt[blockIdx.z];
  unsigned short* WT = Tt[blockIdx.z];
  __shared__ float tile[32][33];
  const int tx = threadIdx.x & 31;
  const int ty = threadIdx.x >> 5;
  const int x0 = blockIdx.x * 32;
  const int y0 = blockIdx.y * 32;
#pragma unroll
  for (int i = 0; i < 32; i += 8)
    tile[ty + i][tx] = W[(size_t)(y0 + ty + i) * DM + x0 + tx];
  __syncthreads();
#pragma unroll
  for (int i = 0; i < 32; i += 8)
    WT[(size_t)(x0 + ty + i) * DM + y0 + tx] = f2bf(tile[tx][ty + i]);
}

// ---------------------------------------------------------------------------
// fp32 -> bf16 convert, 8 elems/thread, vectorized
// ---------------------------------------------------------------------------
__global__ __launch_bounds__(256) void cvt_bf16_kernel(
    const float* __restrict__ x, unsigned short* __restrict__ y) {
  const size_t i = ((size_t)blockIdx.x * 256 + threadIdx.x) * 8;
  float4 a = *(const float4*)(x + i);
  float4 b = *(const float4*)(x + i + 4);
  uint4 p = {pack2(a.x, a.y), pack2(a.z, a.w), pack2(b.x, b.y), pack2(b.z, b.w)};
  *(uint4*)(y + i) = p;
}

// ---------------------------------------------------------------------------
// GEMM (m97 structure): C = A(8192x1024 bf16) * BT^T + bias.
// 128x128 tile, BK=32, 256 thr (4 waves, 4x4 16x16x32 frags each).
// Staging via global_load_lds width-16 into LINEAR LDS [128][32].
// OUTMODE 0: bf16 out scaled, head layout [B,H,L,DH].
// OUTMODE 1: fp32 row-major.
// OUTMODE 2: bf16 out, TRANSPOSED head layout [B,H,DH,L]  (for V)
// Bijective XCD swizzle over the 512-block grid (nwg % 8 == 0).
// ---------------------------------------------------------------------------
template <int OUTMODE>
__global__ __launch_bounds__(256) void gemm_bf16_kernel(
    const unsigned short* __restrict__ A, const unsigned short* __restrict__ BT,
    const float* __restrict__ bias, void* __restrict__ Cptr, float scale) {
  constexpr int K = DM, N = DM;
  __shared__ unsigned short As[128 * 32];
  __shared__ unsigned short Bs[128 * 32];
  const int t = threadIdx.x;
  const int lane = t & 63;
  const int w = t >> 6;
  const int wr = w >> 1, wc = w & 1;
  const int fr = lane & 15, kg = lane >> 4;

  // XCD-aware swizzle: consecutive swz within an XCD share A row-panels
  const int flat = blockIdx.y * gridDim.x + blockIdx.x;
  const int cpx = (gridDim.x * gridDim.y) >> 3;  // nwg/8, nwg%8==0
  const int swz = (flat & 7) * cpx + (flat >> 3);
  const int m0 = (swz / gridDim.x) * 128;
  const int n0 = (swz % gridDim.x) * 128;

  // staging: lane covers row (lane>>2), col-chunk (lane&3)*8 of a [64][32] half
  const int grow = lane >> 2, gcol8 = (lane & 3) * 8;

  f32x4 acc[4][4] = {};

  for (int kt = 0; kt < K / 32; ++kt) {
    const int k0 = kt * 32;
#pragma unroll
    for (int i = 0; i < 2; i++) {
      gload16(A + (size_t)(m0 + i * 64 + w * 16 + grow) * K + k0 + gcol8,
              &As[(i * 256 + w * 64 + lane) * 8]);
      gload16(BT + (size_t)(n0 + i * 64 + w * 16 + grow) * K + k0 + gcol8,
              &Bs[(i * 256 + w * 64 + lane) * 8]);
    }
    __syncthreads();  // drains vmcnt -> LDS tiles complete

    bf16x8 af[4], bfr[4];
#pragma unroll
    for (int i = 0; i < 4; i++)
      af[i] = *(const bf16x8*)&As[(wr * 64 + i * 16 + fr) * 32 + kg * 8];
#pragma unroll
    for (int i = 0; i < 4; i++)
      bfr[i] = *(const bf16x8*)&Bs[(wc * 64 + i * 16 + fr) * 32 + kg * 8];
#pragma unroll
    for (int i = 0; i < 4; i++)
#pragma unroll
      for (int j = 0; j < 4; j++)
        acc[i][j] = __builtin_amdgcn_mfma_f32_16x16x32_bf16(af[i], bfr[j], acc[i][j], 0, 0, 0);
    __syncthreads();
  }

#pragma unroll
  for (int j = 0; j < 4; j++) {
    const int gcol = n0 + wc * 64 + j * 16 + fr;
    const float bv = bias[gcol];
    const int h = gcol >> 6, dh = gcol & 63;
#pragma unroll
    for (int i = 0; i < 4; i++) {
      const int grow0 = m0 + wr * 64 + i * 16 + kg * 4;
      if (OUTMODE == 2) {
        const int b = grow0 >> 11, l = grow0 & 2047;
        uint2 pk;
        pk.x = pack2(acc[i][j][0] + bv, acc[i][j][1] + bv);
        pk.y = pack2(acc[i][j][2] + bv, acc[i][j][3] + bv);
        *(uint2*)((unsigned short*)Cptr +
                  ((size_t)((b * HEADS + h) * DH + dh)) * LL + l) = pk;
      } else {
#pragma unroll
        for (int r = 0; r < 4; r++) {
          const int grow2 = grow0 + r;
          if (OUTMODE == 0) {
            const float val = (acc[i][j][r] + bv) * scale;
            const int b = grow2 >> 11, l = grow2 & 2047;
            ((unsigned short*)Cptr)[(((size_t)(b * HEADS + h) * LL + l) << 6) + dh] = f2bf(val);
          } else {
            ((float*)Cptr)[(size_t)grow2 * N + gcol] = acc[i][j][r] + bv;
          }
        }
      }
    }
  }
}

// scale = 0.125 * log2(e) folded into Q so attention softmax can use exp2
#define QSCALE 0.18033688011112042f

// ---------------------------------------------------------------------------
// Causal flash attention, swapped-operand 32x32x16, 8-wave blocks.
// (unchanged from round 5)
// ---------------------------------------------------------------------------
#define PAD 78
__global__ __launch_bounds__(512) void attn_kernel(
    const unsigned short* __restrict__ Qh, const unsigned short* __restrict__ Kh,
    const unsigned short* __restrict__ VhT, unsigned short* __restrict__ O) {
  __shared__ unsigned short Ks[2][64][PAD];
  __shared__ unsigned short VTs[2][64][PAD];  // [dh][kv]
  const int t = threadIdx.x, lane = t & 63, w = t >> 6;  // w in 0..7
  const int lo5 = lane & 31, hi = lane >> 5;
  const int bh = blockIdx.y;
  const int qi = (int)gridDim.x - 1 - (int)blockIdx.x;  // longest-first
  const int q0 = qi * 256;
  const size_t base = (size_t)bh * LL * DH;
  const int qrow = q0 + w * 32 + lo5;  // this lane's q row

  // Q fragments: B-operand, col = q = lane&31, k = kc*16 + hi*8 + j
  bf16x8 qf[4];
  {
    const unsigned short* Qb = Qh + base + (size_t)qrow * DH + hi * 8;
#pragma unroll
    for (int kc = 0; kc < 4; kc++) qf[kc] = *(const bf16x8*)(Qb + kc * 16);
  }

  float m_run = -INFINITY, l_run = 0.f;
  f32x16 oacc[2] = {};  // D[dh][q]

  // staging: [64][64] bf16 tile, 512 threads x one 8-elem chunk each
  const int rA = t >> 3, kA = (t & 7) * 8;
  const unsigned short* Kb = Kh + base;
  const unsigned short* Vb = VhT + base;  // [dh][l]

  const int ntiles = 4 * (qi + 1);
  const int my_last = (q0 + w * 32 + 31) >> 6;  // last tile this wave needs

  // prologue: tile 0 -> regs -> buf0
  uint4 kr = *(const uint4*)(Kb + (size_t)rA * DH + kA);
  uint4 vr = *(const uint4*)(Vb + (size_t)rA * LL + kA);
  *(uint4*)&Ks[0][rA][kA] = kr;
  *(uint4*)&VTs[0][rA][kA] = vr;

  for (int jt = 0; jt < ntiles; ++jt) {
    const int cur = jt & 1;
    // issue next tile's global loads (consumed after compute)
    if (jt + 1 < ntiles) {
      const int kv1 = (jt + 1) * 64;
      kr = *(const uint4*)(Kb + (size_t)(kv1 + rA) * DH + kA);
      vr = *(const uint4*)(Vb + (size_t)rA * LL + kv1 + kA);
    }
    __syncthreads();  // buf[cur] writes from prev iter visible

    if (jt <= my_last) {
      // S^T = K * Q^T : two 32x32 tiles along kv, K-dim = Dh = 64
      f32x16 s2[2] = {};
      __builtin_amdgcn_s_setprio(1);
#pragma unroll
      for (int tt = 0; tt < 2; tt++)
#pragma unroll
        for (int kc = 0; kc < 4; kc++) {
          bf16x8 kf = *(const bf16x8*)&Ks[cur][tt * 32 + lo5][kc * 16 + hi * 8];
          s2[tt] = __builtin_amdgcn_mfma_f32_32x32x16_bf16(kf, qf[kc], s2[tt], 0, 0, 0);
        }
      __builtin_amdgcn_s_setprio(0);

      // causal mask (only tiles overlapping this wave's diagonal)
      const int kv0 = jt * 64;
      if (kv0 + 63 > q0 + w * 32) {
        const int thr = qrow - kv0 - 4 * hi;
#pragma unroll
        for (int tt = 0; tt < 2; tt++)
#pragma unroll
          for (int i = 0; i < 16; i++) {
            const int kvoff = tt * 32 + (i & 3) + 8 * (i >> 2);
            s2[tt][i] = (kvoff > thr) ? -1e30f : s2[tt][i];
          }
      }

      // row max: in-lane tree + partner half
      float mx;
      {
        float m8[8];
#pragma unroll
        for (int i = 0; i < 8; i++)
          m8[i] = fmaxf(fmaxf(s2[0][i], s2[0][i + 8]), fmaxf(s2[1][i], s2[1][i + 8]));
#pragma unroll
        for (int st = 4; st > 0; st >>= 1)
#pragma unroll
          for (int i = 0; i < st; i++) m8[i] = fmaxf(m8[i], m8[i + st]);
        mx = m8[0];
      }
      mx = fmaxf(mx, __shfl_xor(mx, 32));

      // defer-max: only rescale when some row's max grew by >8 (2^8 P-bound)
      if (__any(mx > m_run + 8.0f)) {
        const float mnew = fmaxf(m_run, mx);
        const float corr = exp2f(m_run - mnew);
        m_run = mnew;
        l_run *= corr;
#pragma unroll
        for (int od = 0; od < 2; od++)
#pragma unroll
          for (int i = 0; i < 16; i++) oacc[od][i] *= corr;
      }

      // p = exp2(s - m)   (logits pre-scaled by log2e at the Q projection)
#pragma unroll
      for (int tt = 0; tt < 2; tt++)
#pragma unroll
        for (int i = 0; i < 16; i++) s2[tt][i] = exp2f(s2[tt][i] - m_run);

      // row sum: in-lane tree + partner half
      float rs;
      {
        float a8[8];
#pragma unroll
        for (int i = 0; i < 8; i++)
          a8[i] = (s2[0][i] + s2[0][i + 8]) + (s2[1][i] + s2[1][i + 8]);
#pragma unroll
        for (int st = 4; st > 0; st >>= 1)
#pragma unroll
          for (int i = 0; i < st; i++) a8[i] += a8[i + st];
        rs = a8[0];
      }
      rs += __shfl_xor(rs, 32);
      l_run += rs;

      // build P B-operand fragments: pa[ks] holds kv = ks*16 + hi*8 + j
      union U8 { uint4 u; bf16x8 v; } pa[4];
#pragma unroll
      for (int ks = 0; ks < 4; ks++) {
        const int tt = ks >> 1, b0 = (ks & 1) * 8;
        const unsigned int w0 = pack2(s2[tt][b0 + 0], s2[tt][b0 + 1]);
        const unsigned int w1 = pack2(s2[tt][b0 + 2], s2[tt][b0 + 3]);
        const unsigned int w2 = pack2(s2[tt][b0 + 4], s2[tt][b0 + 5]);
        const unsigned int w3 = pack2(s2[tt][b0 + 6], s2[tt][b0 + 7]);
        const unsigned int p0 = (unsigned int)__shfl_xor((int)w0, 32);
        const unsigned int p1 = (unsigned int)__shfl_xor((int)w1, 32);
        const unsigned int p2 = (unsigned int)__shfl_xor((int)w2, 32);
        const unsigned int p3 = (unsigned int)__shfl_xor((int)w3, 32);
        pa[ks].u = hi ? make_uint4(p2, p3, w2, w3) : make_uint4(w0, w1, p0, p1);
      }

      // O^T += VT * P : D[dh][q]
      __builtin_amdgcn_s_setprio(1);
#pragma unroll
      for (int od = 0; od < 2; od++)
#pragma unroll
        for (int ks = 0; ks < 4; ks++) {
          bf16x8 vf = *(const bf16x8*)&VTs[cur][od * 32 + lo5][ks * 16 + hi * 8];
          oacc[od] = __builtin_amdgcn_mfma_f32_32x32x16_bf16(vf, pa[ks].v, oacc[od], 0, 0, 0);
        }
      __builtin_amdgcn_s_setprio(0);
    }

    // stage next tile into the other buffer (visible after next barrier)
    if (jt + 1 < ntiles) {
      *(uint4*)&Ks[cur ^ 1][rA][kA] = kr;
      *(uint4*)&VTs[cur ^ 1][rA][kA] = vr;
    }
  }

  // epilogue: O[b][l][h*64+dh] bf16; lane's q = qrow, dh = crow(reg,hi)+od*32
  const float linv = 1.f / l_run;
  const int b = bh >> 4, h = bh & 15;
  unsigned short* Ob = O + ((size_t)(b * LL + qrow) * DM) + h * DH;
#pragma unroll
  for (int od = 0; od < 2; od++)
#pragma unroll
    for (int m = 0; m < 8; m++) {
      const int dh0 = od * 32 + ((2 * m) & 3) + 8 * ((2 * m) >> 2) + 4 * hi;
      const unsigned int pk =
          pack2(oacc[od][2 * m] * linv, oacc[od][2 * m + 1] * linv);
      *(unsigned int*)(Ob + dh0) = pk;
    }
}

// ---------------------------------------------------------------------------
extern "C" void kernel_launch(void* const* d_in, const int* in_sizes, int n_in,
                              void* d_out, int out_size, void* d_ws, size_t ws_size,
                              hipStream_t stream) {
  (void)in_sizes; (void)n_in; (void)out_size; (void)ws_size;
  const float* q  = (const float*)d_in[0];
  const float* k  = (const float*)d_in[1];
  const float* v  = (const float*)d_in[2];
  const float* Wq = (const float*)d_in[3];
  const float* bq = (const float*)d_in[4];
  const float* Wk = (const float*)d_in[5];
  const float* bk = (const float*)d_in[6];
  const float* Wv = (const float*)d_in[7];
  const float* bv = (const float*)d_in[8];
  const float* Wo = (const float*)d_in[9];
  const float* bo = (const float*)d_in[10];

  char* ws = (char*)d_ws;
  const size_t WSZ = (size_t)DM * DM * 2;          // 2 MB per transposed weight
  const size_t HSZ = (size_t)MROWS * DM * 2;       // 16 MB per bf16 activation
  unsigned short* WqT = (unsigned short*)(ws);
  unsigned short* WkT = (unsigned short*)(ws + WSZ);
  unsigned short* WvT = (unsigned short*)(ws + 2 * WSZ);
  unsigned short* WoT = (unsigned short*)(ws + 3 * WSZ);
  unsigned short* Qh  = (unsigned short*)(ws + 4 * WSZ);
  unsigned short* Kh  = (unsigned short*)(ws + 4 * WSZ + HSZ);
  unsigned short* VhT = (unsigned short*)(ws + 4 * WSZ + 2 * HSZ);
  unsigned short* X   = (unsigned short*)(ws + 4 * WSZ + 3 * HSZ);  // cvt scratch, later Oc
  unsigned short* Oc  = X;  // safe: X's cvt contents dead once V-GEMM finishes

  transpose_w_kernel<<<dim3(32, 32, 4), 256, 0, stream>>>(
      Wq, Wk, Wv, Wo, WqT, WkT, WvT, WoT);

  const dim3 cgrid(MROWS * DM / (256 * 8));
  const dim3 ggrid(DM / 128, MROWS / 128);

  cvt_bf16_kernel<<<cgrid, 256, 0, stream>>>(q, X);
  gemm_bf16_kernel<0><<<ggrid, 256, 0, stream>>>(X, WqT, bq, Qh, QSCALE);
  cvt_bf16_kernel<<<cgrid, 256, 0, stream>>>(k, X);
  gemm_bf16_kernel<0><<<ggrid, 256, 0, stream>>>(X, WkT, bk, Kh, 1.0f);
  cvt_bf16_kernel<<<cgrid, 256, 0, stream>>>(v, X);
  gemm_bf16_kernel<2><<<ggrid, 256, 0, stream>>>(X, WvT, bv, VhT, 1.0f);

  attn_kernel<<<dim3(LL / 256, BB * HEADS), 512, 0, stream>>>(Qh, Kh, VhT, Oc);

  gemm_bf16_kernel<1><<<ggrid, 256, 0, stream>>>(Oc, WoT, bo, (float*)d_out, 1.0f);
}

// Round 7
// 266.748 us; speedup vs baseline: 1.8268x; 1.0060x over previous
//
#include <hip/hip_runtime.h>

#define DM 1024
#define HEADS 16
#define DH 64
#define BB 4
#define LL 2048
#define MROWS (BB * LL) /* 8192 */

typedef __bf16 bf16x8 __attribute__((ext_vector_type(8)));
typedef float f32x4 __attribute__((ext_vector_type(4)));
typedef float f32x16 __attribute__((ext_vector_type(16)));

// HW round-to-nearest-even f32->bf16 via compiler (emits v_cvt_pk_bf16_f32)
__device__ __forceinline__ unsigned short f2bf(float f) {
  __bf16 h = (__bf16)f;
  return __builtin_bit_cast(unsigned short, h);
}
__device__ __forceinline__ unsigned int pack2(float a, float b) {
  return (unsigned int)f2bf(a) | ((unsigned int)f2bf(b) << 16);
}

// async global->LDS, 16B per lane; LDS dest is wave-uniform base + lane*16
__device__ __forceinline__ void gload16(const unsigned short* g, unsigned short* l) {
  __builtin_amdgcn_global_load_lds(
      (const __attribute__((address_space(1))) unsigned int*)(const void*)g,
      (__attribute__((address_space(3))) unsigned int*)(void*)l, 16, 0, 0);
}

// ---------------------------------------------------------------------------
// Weight transpose + bf16 convert: WT[n][k] = bf16(W[k][n]), 1024x1024, z=4
// ---------------------------------------------------------------------------
__global__ __launch_bounds__(256) void transpose_w_kernel(
    const float* __restrict__ W0, const float* __restrict__ W1,
    const float* __restrict__ W2, const float* __restrict__ W3,
    unsigned short* __restrict__ T0, unsigned short* __restrict__ T1,
    unsigned short* __restrict__ T2, unsigned short* __restrict__ T3) {
  const float* Wt[4] = {W0, W1, W2, W3};
  unsigned short* Tt[4] = {T0, T1, T2, T3};
  const float* W = Wt[blockIdx.z];
  unsigned short* WT = Tt[blockIdx.z];
  __shared__ float tile[32][33];
  const int tx = threadIdx.x & 31;
  const int ty = threadIdx.x >> 5;
  const int x0 = blockIdx.x * 32;
  const int y0 = blockIdx.y * 32;
#pragma unroll
  for (int i = 0; i < 32; i += 8)
    tile[ty + i][tx] = W[(size_t)(y0 + ty + i) * DM + x0 + tx];
  __syncthreads();
#pragma unroll
  for (int i = 0; i < 32; i += 8)
    WT[(size_t)(x0 + ty + i) * DM + y0 + tx] = f2bf(tile[tx][ty + i]);
}

// ---------------------------------------------------------------------------
// fp32 -> bf16 convert, 8 elems/thread, vectorized
// ---------------------------------------------------------------------------
__global__ __launch_bounds__(256) void cvt_bf16_kernel(
    const float* __restrict__ x, unsigned short* __restrict__ y) {
  const size_t i = ((size_t)blockIdx.x * 256 + threadIdx.x) * 8;
  float4 a = *(const float4*)(x + i);
  float4 b = *(const float4*)(x + i + 4);
  uint4 p = {pack2(a.x, a.y), pack2(a.z, a.w), pack2(b.x, b.y), pack2(b.z, b.w)};
  *(uint4*)(y + i) = p;
}

// ---------------------------------------------------------------------------
// GEMM (m97 structure): C = A(8192x1024 bf16) * BT^T + bias.
// 128x128 tile, BK=32, 256 thr (4 waves, 4x4 16x16x32 frags each).
// Staging via global_load_lds width-16 into LINEAR LDS [128][32].
// OUTMODE 0: bf16 out scaled, head layout [B,H,L,DH].
// OUTMODE 1: fp32 row-major.
// OUTMODE 2: bf16 out, TRANSPOSED head layout [B,H,DH,L]  (for V)
// Bijective XCD swizzle over the 512-block grid (nwg % 8 == 0).
// ---------------------------------------------------------------------------
template <int OUTMODE>
__global__ __launch_bounds__(256) void gemm_bf16_kernel(
    const unsigned short* __restrict__ A, const unsigned short* __restrict__ BT,
    const float* __restrict__ bias, void* __restrict__ Cptr, float scale) {
  constexpr int K = DM, N = DM;
  __shared__ unsigned short As[128 * 32];
  __shared__ unsigned short Bs[128 * 32];
  const int t = threadIdx.x;
  const int lane = t & 63;
  const int w = t >> 6;
  const int wr = w >> 1, wc = w & 1;
  const int fr = lane & 15, kg = lane >> 4;

  // XCD-aware swizzle: consecutive swz within an XCD share A row-panels
  const int flat = blockIdx.y * gridDim.x + blockIdx.x;
  const int cpx = (gridDim.x * gridDim.y) >> 3;  // nwg/8, nwg%8==0
  const int swz = (flat & 7) * cpx + (flat >> 3);
  const int m0 = (swz / gridDim.x) * 128;
  const int n0 = (swz % gridDim.x) * 128;

  // staging: lane covers row (lane>>2), col-chunk (lane&3)*8 of a [64][32] half
  const int grow = lane >> 2, gcol8 = (lane & 3) * 8;

  f32x4 acc[4][4] = {};

  for (int kt = 0; kt < K / 32; ++kt) {
    const int k0 = kt * 32;
#pragma unroll
    for (int i = 0; i < 2; i++) {
      gload16(A + (size_t)(m0 + i * 64 + w * 16 + grow) * K + k0 + gcol8,
              &As[(i * 256 + w * 64 + lane) * 8]);
      gload16(BT + (size_t)(n0 + i * 64 + w * 16 + grow) * K + k0 + gcol8,
              &Bs[(i * 256 + w * 64 + lane) * 8]);
    }
    __syncthreads();  // drains vmcnt -> LDS tiles complete

    bf16x8 af[4], bfr[4];
#pragma unroll
    for (int i = 0; i < 4; i++)
      af[i] = *(const bf16x8*)&As[(wr * 64 + i * 16 + fr) * 32 + kg * 8];
#pragma unroll
    for (int i = 0; i < 4; i++)
      bfr[i] = *(const bf16x8*)&Bs[(wc * 64 + i * 16 + fr) * 32 + kg * 8];
#pragma unroll
    for (int i = 0; i < 4; i++)
#pragma unroll
      for (int j = 0; j < 4; j++)
        acc[i][j] = __builtin_amdgcn_mfma_f32_16x16x32_bf16(af[i], bfr[j], acc[i][j], 0, 0, 0);
    __syncthreads();
  }

#pragma unroll
  for (int j = 0; j < 4; j++) {
    const int gcol = n0 + wc * 64 + j * 16 + fr;
    const float bv = bias[gcol];
    const int h = gcol >> 6, dh = gcol & 63;
#pragma unroll
    for (int i = 0; i < 4; i++) {
      const int grow0 = m0 + wr * 64 + i * 16 + kg * 4;
      if (OUTMODE == 2) {
        const int b = grow0 >> 11, l = grow0 & 2047;
        uint2 pk;
        pk.x = pack2(acc[i][j][0] + bv, acc[i][j][1] + bv);
        pk.y = pack2(acc[i][j][2] + bv, acc[i][j][3] + bv);
        *(uint2*)((unsigned short*)Cptr +
                  ((size_t)((b * HEADS + h) * DH + dh)) * LL + l) = pk;
      } else {
#pragma unroll
        for (int r = 0; r < 4; r++) {
          const int grow2 = grow0 + r;
          if (OUTMODE == 0) {
            const float val = (acc[i][j][r] + bv) * scale;
            const int b = grow2 >> 11, l = grow2 & 2047;
            ((unsigned short*)Cptr)[(((size_t)(b * HEADS + h) * LL + l) << 6) + dh] = f2bf(val);
          } else {
            ((float*)Cptr)[(size_t)grow2 * N + gcol] = acc[i][j][r] + bv;
          }
        }
      }
    }
  }
}

// scale = 0.125 * log2(e) folded into Q so attention softmax can use exp2
#define QSCALE 0.18033688011112042f

// ---------------------------------------------------------------------------
// Causal flash attention, swapped-operand 32x32x16, 4-wave / 256-thr blocks.
// Grid (qtile=16, bh=64) = 1024 blocks -> 4 blocks/CU (LDS 4x39.9KB = 160KB),
// 16 waves/CU.  Each wave owns 32 q-rows (q = q0 + w*32 + (lane&31));
// KV tiles of 64; Dh = 64.  Double-buffered K/V LDS, 1 barrier/iter;
// next tile prefetched into regs before the barrier.
// Waves skip compute (not barriers/staging) past their diagonal.
// Defer-max rescale skip; LDS stride 78 -> conflict-free b128 reads.
// ---------------------------------------------------------------------------
#define PAD 78
__global__ __launch_bounds__(256) void attn_kernel(
    const unsigned short* __restrict__ Qh, const unsigned short* __restrict__ Kh,
    const unsigned short* __restrict__ VhT, unsigned short* __restrict__ O) {
  __shared__ unsigned short Ks[2][64][PAD];
  __shared__ unsigned short VTs[2][64][PAD];  // [dh][kv]
  const int t = threadIdx.x, lane = t & 63, w = t >> 6;  // w in 0..3
  const int lo5 = lane & 31, hi = lane >> 5;
  const int bh = blockIdx.y;
  const int qi = (int)gridDim.x - 1 - (int)blockIdx.x;  // longest-first
  const int q0 = qi * 128;
  const size_t base = (size_t)bh * LL * DH;
  const int qrow = q0 + w * 32 + lo5;  // this lane's q row

  // Q fragments: B-operand, col = q = lane&31, k = kc*16 + hi*8 + j
  bf16x8 qf[4];
  {
    const unsigned short* Qb = Qh + base + (size_t)qrow * DH + hi * 8;
#pragma unroll
    for (int kc = 0; kc < 4; kc++) qf[kc] = *(const bf16x8*)(Qb + kc * 16);
  }

  float m_run = -INFINITY, l_run = 0.f;
  f32x16 oacc[2] = {};  // D[dh][q]

  // staging: [64][64] bf16 tile, 256 threads x two 8-elem chunks per matrix
  const int rA = t >> 3, kA = (t & 7) * 8;  // rows 0..31
  const int rB = rA + 32;                   // rows 32..63
  const unsigned short* Kb = Kh + base;
  const unsigned short* Vb = VhT + base;  // [dh][l]

  const int ntiles = 2 * (qi + 1);
  const int my_last = (q0 + w * 32 + 31) >> 6;  // last tile this wave needs

  // prologue: tile 0 -> regs -> buf0
  uint4 kr0 = *(const uint4*)(Kb + (size_t)rA * DH + kA);
  uint4 kr1 = *(const uint4*)(Kb + (size_t)rB * DH + kA);
  uint4 vr0 = *(const uint4*)(Vb + (size_t)rA * LL + kA);
  uint4 vr1 = *(const uint4*)(Vb + (size_t)rB * LL + kA);
  *(uint4*)&Ks[0][rA][kA] = kr0;
  *(uint4*)&Ks[0][rB][kA] = kr1;
  *(uint4*)&VTs[0][rA][kA] = vr0;
  *(uint4*)&VTs[0][rB][kA] = vr1;

  for (int jt = 0; jt < ntiles; ++jt) {
    const int cur = jt & 1;
    // issue next tile's global loads (consumed after compute)
    if (jt + 1 < ntiles) {
      const int kv1 = (jt + 1) * 64;
      kr0 = *(const uint4*)(Kb + (size_t)(kv1 + rA) * DH + kA);
      kr1 = *(const uint4*)(Kb + (size_t)(kv1 + rB) * DH + kA);
      vr0 = *(const uint4*)(Vb + (size_t)rA * LL + kv1 + kA);
      vr1 = *(const uint4*)(Vb + (size_t)rB * LL + kv1 + kA);
    }
    __syncthreads();  // buf[cur] writes from prev iter visible

    if (jt <= my_last) {
      // S^T = K * Q^T : two 32x32 tiles along kv, K-dim = Dh = 64
      f32x16 s2[2] = {};
      __builtin_amdgcn_s_setprio(1);
#pragma unroll
      for (int tt = 0; tt < 2; tt++)
#pragma unroll
        for (int kc = 0; kc < 4; kc++) {
          bf16x8 kf = *(const bf16x8*)&Ks[cur][tt * 32 + lo5][kc * 16 + hi * 8];
          s2[tt] = __builtin_amdgcn_mfma_f32_32x32x16_bf16(kf, qf[kc], s2[tt], 0, 0, 0);
        }
      __builtin_amdgcn_s_setprio(0);

      // causal mask (only tiles overlapping this wave's diagonal)
      const int kv0 = jt * 64;
      if (kv0 + 63 > q0 + w * 32) {
        const int thr = qrow - kv0 - 4 * hi;
#pragma unroll
        for (int tt = 0; tt < 2; tt++)
#pragma unroll
          for (int i = 0; i < 16; i++) {
            const int kvoff = tt * 32 + (i & 3) + 8 * (i >> 2);
            s2[tt][i] = (kvoff > thr) ? -1e30f : s2[tt][i];
          }
      }

      // row max: in-lane tree + partner half
      float mx;
      {
        float m8[8];
#pragma unroll
        for (int i = 0; i < 8; i++)
          m8[i] = fmaxf(fmaxf(s2[0][i], s2[0][i + 8]), fmaxf(s2[1][i], s2[1][i + 8]));
#pragma unroll
        for (int st = 4; st > 0; st >>= 1)
#pragma unroll
          for (int i = 0; i < st; i++) m8[i] = fmaxf(m8[i], m8[i + st]);
        mx = m8[0];
      }
      mx = fmaxf(mx, __shfl_xor(mx, 32));

      // defer-max: only rescale when some row's max grew by >8 (2^8 P-bound)
      if (__any(mx > m_run + 8.0f)) {
        const float mnew = fmaxf(m_run, mx);
        const float corr = __builtin_amdgcn_exp2f(m_run - mnew);
        m_run = mnew;
        l_run *= corr;
#pragma unroll
        for (int od = 0; od < 2; od++)
#pragma unroll
          for (int i = 0; i < 16; i++) oacc[od][i] *= corr;
      }

      // p = exp2(s - m)   (logits pre-scaled by log2e at the Q projection)
#pragma unroll
      for (int tt = 0; tt < 2; tt++)
#pragma unroll
        for (int i = 0; i < 16; i++)
          s2[tt][i] = __builtin_amdgcn_exp2f(s2[tt][i] - m_run);

      // row sum: in-lane tree + partner half
      float rs;
      {
        float a8[8];
#pragma unroll
        for (int i = 0; i < 8; i++)
          a8[i] = (s2[0][i] + s2[0][i + 8]) + (s2[1][i] + s2[1][i + 8]);
#pragma unroll
        for (int st = 4; st > 0; st >>= 1)
#pragma unroll
          for (int i = 0; i < st; i++) a8[i] += a8[i + st];
        rs = a8[0];
      }
      rs += __shfl_xor(rs, 32);
      l_run += rs;

      // build P B-operand fragments: pa[ks] holds kv = ks*16 + hi*8 + j
      union U8 { uint4 u; bf16x8 v; } pa[4];
#pragma unroll
      for (int ks = 0; ks < 4; ks++) {
        const int tt = ks >> 1, b0 = (ks & 1) * 8;
        const unsigned int w0 = pack2(s2[tt][b0 + 0], s2[tt][b0 + 1]);
        const unsigned int w1 = pack2(s2[tt][b0 + 2], s2[tt][b0 + 3]);
        const unsigned int w2 = pack2(s2[tt][b0 + 4], s2[tt][b0 + 5]);
        const unsigned int w3 = pack2(s2[tt][b0 + 6], s2[tt][b0 + 7]);
        const unsigned int p0 = (unsigned int)__shfl_xor((int)w0, 32);
        const unsigned int p1 = (unsigned int)__shfl_xor((int)w1, 32);
        const unsigned int p2 = (unsigned int)__shfl_xor((int)w2, 32);
        const unsigned int p3 = (unsigned int)__shfl_xor((int)w3, 32);
        pa[ks].u = hi ? make_uint4(p2, p3, w2, w3) : make_uint4(w0, w1, p0, p1);
      }

      // O^T += VT * P : D[dh][q]
      __builtin_amdgcn_s_setprio(1);
#pragma unroll
      for (int od = 0; od < 2; od++)
#pragma unroll
        for (int ks = 0; ks < 4; ks++) {
          bf16x8 vf = *(const bf16x8*)&VTs[cur][od * 32 + lo5][ks * 16 + hi * 8];
          oacc[od] = __builtin_amdgcn_mfma_f32_32x32x16_bf16(vf, pa[ks].v, oacc[od], 0, 0, 0);
        }
      __builtin_amdgcn_s_setprio(0);
    }

    // stage next tile into the other buffer (visible after next barrier)
    if (jt + 1 < ntiles) {
      *(uint4*)&Ks[cur ^ 1][rA][kA] = kr0;
      *(uint4*)&Ks[cur ^ 1][rB][kA] = kr1;
      *(uint4*)&VTs[cur ^ 1][rA][kA] = vr0;
      *(uint4*)&VTs[cur ^ 1][rB][kA] = vr1;
    }
  }

  // epilogue: O[b][l][h*64+dh] bf16; lane's q = qrow, dh = crow(reg,hi)+od*32
  const float linv = 1.f / l_run;
  const int b = bh >> 4, h = bh & 15;
  unsigned short* Ob = O + ((size_t)(b * LL + qrow) * DM) + h * DH;
#pragma unroll
  for (int od = 0; od < 2; od++)
#pragma unroll
    for (int m = 0; m < 8; m++) {
      const int dh0 = od * 32 + ((2 * m) & 3) + 8 * ((2 * m) >> 2) + 4 * hi;
      const unsigned int pk =
          pack2(oacc[od][2 * m] * linv, oacc[od][2 * m + 1] * linv);
      *(unsigned int*)(Ob + dh0) = pk;
    }
}

// ---------------------------------------------------------------------------
extern "C" void kernel_launch(void* const* d_in, const int* in_sizes, int n_in,
                              void* d_out, int out_size, void* d_ws, size_t ws_size,
                              hipStream_t stream) {
  (void)in_sizes; (void)n_in; (void)out_size; (void)ws_size;
  const float* q  = (const float*)d_in[0];
  const float* k  = (const float*)d_in[1];
  const float* v  = (const float*)d_in[2];
  const float* Wq = (const float*)d_in[3];
  const float* bq = (const float*)d_in[4];
  const float* Wk = (const float*)d_in[5];
  const float* bk = (const float*)d_in[6];
  const float* Wv = (const float*)d_in[7];
  const float* bv = (const float*)d_in[8];
  const float* Wo = (const float*)d_in[9];
  const float* bo = (const float*)d_in[10];

  char* ws = (char*)d_ws;
  const size_t WSZ = (size_t)DM * DM * 2;          // 2 MB per transposed weight
  const size_t HSZ = (size_t)MROWS * DM * 2;       // 16 MB per bf16 activation
  unsigned short* WqT = (unsigned short*)(ws);
  unsigned short* WkT = (unsigned short*)(ws + WSZ);
  unsigned short* WvT = (unsigned short*)(ws + 2 * WSZ);
  unsigned short* WoT = (unsigned short*)(ws + 3 * WSZ);
  unsigned short* Qh  = (unsigned short*)(ws + 4 * WSZ);
  unsigned short* Kh  = (unsigned short*)(ws + 4 * WSZ + HSZ);
  unsigned short* VhT = (unsigned short*)(ws + 4 * WSZ + 2 * HSZ);
  unsigned short* X   = (unsigned short*)(ws + 4 * WSZ + 3 * HSZ);  // cvt scratch, later Oc
  unsigned short* Oc  = X;  // safe: X's cvt contents dead once V-GEMM finishes

  transpose_w_kernel<<<dim3(32, 32, 4), 256, 0, stream>>>(
      Wq, Wk, Wv, Wo, WqT, WkT, WvT, WoT);

  const dim3 cgrid(MROWS * DM / (256 * 8));
  const dim3 ggrid(DM / 128, MROWS / 128);

  cvt_bf16_kernel<<<cgrid, 256, 0, stream>>>(q, X);
  gemm_bf16_kernel<0><<<ggrid, 256, 0, stream>>>(X, WqT, bq, Qh, QSCALE);
  cvt_bf16_kernel<<<cgrid, 256, 0, stream>>>(k, X);
  gemm_bf16_kernel<0><<<ggrid, 256, 0, stream>>>(X, WkT, bk, Kh, 1.0f);
  cvt_bf16_kernel<<<cgrid, 256, 0, stream>>>(v, X);
  gemm_bf16_kernel<2><<<ggrid, 256, 0, stream>>>(X, WvT, bv, VhT, 1.0f);

  attn_kernel<<<dim3(LL / 128, BB * HEADS), 256, 0, stream>>>(Qh, Kh, VhT, Oc);

  gemm_bf16_kernel<1><<<ggrid, 256, 0, stream>>>(Oc, WoT, bo, (float*)d_out, 1.0f);
}

// Round 9
// 213.286 us; speedup vs baseline: 2.2847x; 1.2507x over previous
//
#include <hip/hip_runtime.h>

#define DM 1024
#define HEADS 16
#define DH 64
#define BB 4
#define LL 2048
#define MROWS (BB * LL) /* 8192 */

typedef __bf16 bf16x8 __attribute__((ext_vector_type(8)));
typedef float f32x4 __attribute__((ext_vector_type(4)));
typedef float f32x16 __attribute__((ext_vector_type(16)));

// HW round-to-nearest-even f32->bf16 via compiler (emits v_cvt_pk_bf16_f32)
__device__ __forceinline__ unsigned short f2bf(float f) {
  __bf16 h = (__bf16)f;
  return __builtin_bit_cast(unsigned short, h);
}
__device__ __forceinline__ unsigned int pack2(float a, float b) {
  return (unsigned int)f2bf(a) | ((unsigned int)f2bf(b) << 16);
}

// async global->LDS, 16B per lane; LDS dest is wave-uniform base + lane*16
__device__ __forceinline__ void gload16(const unsigned short* g, unsigned short* l) {
  __builtin_amdgcn_global_load_lds(
      (const __attribute__((address_space(1))) unsigned int*)(const void*)g,
      (__attribute__((address_space(3))) unsigned int*)(void*)l, 16, 0, 0);
}

// ---------------------------------------------------------------------------
// Weight transpose + bf16 convert: WT[n][k] = bf16(W[k][n]), 1024x1024, z=4
// ---------------------------------------------------------------------------
__global__ __launch_bounds__(256) void transpose_w_kernel(
    const float* __restrict__ W0, const float* __restrict__ W1,
    const float* __restrict__ W2, const float* __restrict__ W3,
    unsigned short* __restrict__ T0, unsigned short* __restrict__ T1,
    unsigned short* __restrict__ T2, unsigned short* __restrict__ T3) {
  const float* Wt[4] = {W0, W1, W2, W3};
  unsigned short* Tt[4] = {T0, T1, T2, T3};
  const float* W = Wt[blockIdx.z];
  unsigned short* WT = Tt[blockIdx.z];
  __shared__ float tile[32][33];
  const int tx = threadIdx.x & 31;
  const int ty = threadIdx.x >> 5;
  const int x0 = blockIdx.x * 32;
  const int y0 = blockIdx.y * 32;
#pragma unroll
  for (int i = 0; i < 32; i += 8)
    tile[ty + i][tx] = W[(size_t)(y0 + ty + i) * DM + x0 + tx];
  __syncthreads();
#pragma unroll
  for (int i = 0; i < 32; i += 8)
    WT[(size_t)(x0 + ty + i) * DM + y0 + tx] = f2bf(tile[tx][ty + i]);
}

// ---------------------------------------------------------------------------
// fp32 -> bf16 convert, 8 elems/thread, vectorized
// ---------------------------------------------------------------------------
__global__ __launch_bounds__(256) void cvt_bf16_kernel(
    const float* __restrict__ x, unsigned short* __restrict__ y) {
  const size_t i = ((size_t)blockIdx.x * 256 + threadIdx.x) * 8;
  float4 a = *(const float4*)(x + i);
  float4 b = *(const float4*)(x + i + 4);
  uint4 p = {pack2(a.x, a.y), pack2(a.z, a.w), pack2(b.x, b.y), pack2(b.z, b.w)};
  *(uint4*)(y + i) = p;
}

// ---------------------------------------------------------------------------
// GEMM (m97 structure): C = A(8192x1024 bf16) * BT^T + bias.
// 128x128 tile, BK=32, 256 thr (4 waves, 4x4 16x16x32 frags each).
// Staging via global_load_lds width-16 into LINEAR LDS [128][32].
// OUTMODE 0: bf16 out scaled, head layout [B,H,L,DH].
// OUTMODE 1: fp32 row-major.
// OUTMODE 2: bf16 out, TRANSPOSED head layout [B,H,DH,L]  (for V)
// Bijective XCD swizzle over the 512-block grid (nwg % 8 == 0).
// ---------------------------------------------------------------------------
template <int OUTMODE>
__global__ __launch_bounds__(256) void gemm_bf16_kernel(
    const unsigned short* __restrict__ A, const unsigned short* __restrict__ BT,
    const float* __restrict__ bias, void* __restrict__ Cptr, float scale) {
  constexpr int K = DM, N = DM;
  __shared__ unsigned short As[128 * 32];
  __shared__ unsigned short Bs[128 * 32];
  const int t = threadIdx.x;
  const int lane = t & 63;
  const int w = t >> 6;
  const int wr = w >> 1, wc = w & 1;
  const int fr = lane & 15, kg = lane >> 4;

  // XCD-aware swizzle: consecutive swz within an XCD share A row-panels
  const int flat = blockIdx.y * gridDim.x + blockIdx.x;
  const int cpx = (gridDim.x * gridDim.y) >> 3;  // nwg/8, nwg%8==0
  const int swz = (flat & 7) * cpx + (flat >> 3);
  const int m0 = (swz / gridDim.x) * 128;
  const int n0 = (swz % gridDim.x) * 128;

  // staging: lane covers row (lane>>2), col-chunk (lane&3)*8 of a [64][32] half
  const int grow = lane >> 2, gcol8 = (lane & 3) * 8;

  f32x4 acc[4][4] = {};

  for (int kt = 0; kt < K / 32; ++kt) {
    const int k0 = kt * 32;
#pragma unroll
    for (int i = 0; i < 2; i++) {
      gload16(A + (size_t)(m0 + i * 64 + w * 16 + grow) * K + k0 + gcol8,
              &As[(i * 256 + w * 64 + lane) * 8]);
      gload16(BT + (size_t)(n0 + i * 64 + w * 16 + grow) * K + k0 + gcol8,
              &Bs[(i * 256 + w * 64 + lane) * 8]);
    }
    __syncthreads();  // drains vmcnt -> LDS tiles complete

    bf16x8 af[4], bfr[4];
#pragma unroll
    for (int i = 0; i < 4; i++)
      af[i] = *(const bf16x8*)&As[(wr * 64 + i * 16 + fr) * 32 + kg * 8];
#pragma unroll
    for (int i = 0; i < 4; i++)
      bfr[i] = *(const bf16x8*)&Bs[(wc * 64 + i * 16 + fr) * 32 + kg * 8];
#pragma unroll
    for (int i = 0; i < 4; i++)
#pragma unroll
      for (int j = 0; j < 4; j++)
        acc[i][j] = __builtin_amdgcn_mfma_f32_16x16x32_bf16(af[i], bfr[j], acc[i][j], 0, 0, 0);
    __syncthreads();
  }

#pragma unroll
  for (int j = 0; j < 4; j++) {
    const int gcol = n0 + wc * 64 + j * 16 + fr;
    const float bv = bias[gcol];
    const int h = gcol >> 6, dh = gcol & 63;
#pragma unroll
    for (int i = 0; i < 4; i++) {
      const int grow0 = m0 + wr * 64 + i * 16 + kg * 4;
      if (OUTMODE == 2) {
        const int b = grow0 >> 11, l = grow0 & 2047;
        uint2 pk;
        pk.x = pack2(acc[i][j][0] + bv, acc[i][j][1] + bv);
        pk.y = pack2(acc[i][j][2] + bv, acc[i][j][3] + bv);
        *(uint2*)((unsigned short*)Cptr +
                  ((size_t)((b * HEADS + h) * DH + dh)) * LL + l) = pk;
      } else {
#pragma unroll
        for (int r = 0; r < 4; r++) {
          const int grow2 = grow0 + r;
          if (OUTMODE == 0) {
            const float val = (acc[i][j][r] + bv) * scale;
            const int b = grow2 >> 11, l = grow2 & 2047;
            ((unsigned short*)Cptr)[(((size_t)(b * HEADS + h) * LL + l) << 6) + dh] = f2bf(val);
          } else {
            ((float*)Cptr)[(size_t)grow2 * N + gcol] = acc[i][j][r] + bv;
          }
        }
      }
    }
  }
}

// scale = 0.125 * log2(e) folded into Q so attention softmax can use exp2
#define QSCALE 0.18033688011112042f

// ---------------------------------------------------------------------------
// Causal flash attention, swapped-operand 32x32x16, 4-wave / 256-thr blocks.
// UNIFORM WORK: block (px, bh) serially processes q-tiles (15-px) then px,
// so every block runs exactly 34 KV-tile iterations regardless of px ->
// perfect balance under any dispatch mapping.  Grid (8, 64) = 512 blocks,
// 2 blocks/CU.  XCD remap: each XCD owns 8 bh x all 8 pairs (KV set = 4MB
// = one L2).  Per wave: 32 q-rows; KV tiles of 64; Dh = 64.
// Double-buffered K/V LDS, 1 barrier/iter, reg prefetch before barrier.
// Cross-half exchange via __shfl_xor(.,32) (round-7-verified; permlane asm
// reverted -- it was the round-8 NaN suspect).
// Defer-max rescale skip; LDS stride 78 -> conflict-free b128 reads.
// ---------------------------------------------------------------------------
#define PAD 78
__global__ __launch_bounds__(256) void attn_kernel(
    const unsigned short* __restrict__ Qh, const unsigned short* __restrict__ Kh,
    const unsigned short* __restrict__ VhT, unsigned short* __restrict__ O) {
  __shared__ unsigned short Ks[2][64][PAD];
  __shared__ unsigned short VTs[2][64][PAD];  // [dh][kv]
  const int t = threadIdx.x, lane = t & 63, w = t >> 6;  // w in 0..3
  const int lo5 = lane & 31, hi = lane >> 5;

  // XCD remap: f%8 = XCD; give each XCD 8 bh x all 8 pairs
  const int f = (int)(blockIdx.y * gridDim.x + blockIdx.x);
  const int xcd = f & 7, idx = f >> 3;
  const int bh = xcd * 8 + (idx & 7);
  const int px = idx >> 3;  // pair index 0..7

  const size_t base = (size_t)bh * LL * DH;
  const unsigned short* Kb = Kh + base;
  const unsigned short* Vb = VhT + base;  // [dh][l]

  // staging: [64][64] bf16 tile, 256 threads x two 8-elem chunks per matrix
  const int rA = t >> 3, kA = (t & 7) * 8;  // rows 0..31
  const int rB = rA + 32;                   // rows 32..63

  const int b = bh >> 4, h = bh & 15;

  for (int pass = 0; pass < 2; ++pass) {
    const int qi = pass ? px : 15 - px;
    const int q0 = qi * 128;
    const int qrow = q0 + w * 32 + lo5;  // this lane's q row

    // Q fragments: B-operand, col = q = lane&31, k = kc*16 + hi*8 + j
    bf16x8 qf[4];
    {
      const unsigned short* Qb = Qh + base + (size_t)qrow * DH + hi * 8;
#pragma unroll
      for (int kc = 0; kc < 4; kc++) qf[kc] = *(const bf16x8*)(Qb + kc * 16);
    }

    float m_run = -INFINITY, l_run = 0.f;
    f32x16 oacc[2] = {};  // D[dh][q]

    const int ntiles = 2 * (qi + 1);
    const int my_last = (q0 + w * 32 + 31) >> 6;  // last tile this wave needs

    // prologue: tile 0 -> regs -> buf0 (barrier protects prev pass's reads)
    uint4 kr0 = *(const uint4*)(Kb + (size_t)rA * DH + kA);
    uint4 kr1 = *(const uint4*)(Kb + (size_t)rB * DH + kA);
    uint4 vr0 = *(const uint4*)(Vb + (size_t)rA * LL + kA);
    uint4 vr1 = *(const uint4*)(Vb + (size_t)rB * LL + kA);
    __syncthreads();
    *(uint4*)&Ks[0][rA][kA] = kr0;
    *(uint4*)&Ks[0][rB][kA] = kr1;
    *(uint4*)&VTs[0][rA][kA] = vr0;
    *(uint4*)&VTs[0][rB][kA] = vr1;

    for (int jt = 0; jt < ntiles; ++jt) {
      const int cur = jt & 1;
      // issue next tile's global loads (consumed after compute)
      if (jt + 1 < ntiles) {
        const int kv1 = (jt + 1) * 64;
        kr0 = *(const uint4*)(Kb + (size_t)(kv1 + rA) * DH + kA);
        kr1 = *(const uint4*)(Kb + (size_t)(kv1 + rB) * DH + kA);
        vr0 = *(const uint4*)(Vb + (size_t)rA * LL + kv1 + kA);
        vr1 = *(const uint4*)(Vb + (size_t)rB * LL + kv1 + kA);
      }
      __syncthreads();  // buf[cur] writes from prev iter visible

      if (jt <= my_last) {
        // S^T = K * Q^T : two 32x32 tiles along kv, K-dim = Dh = 64
        f32x16 s2[2] = {};
        __builtin_amdgcn_s_setprio(1);
#pragma unroll
        for (int tt = 0; tt < 2; tt++)
#pragma unroll
          for (int kc = 0; kc < 4; kc++) {
            bf16x8 kf = *(const bf16x8*)&Ks[cur][tt * 32 + lo5][kc * 16 + hi * 8];
            s2[tt] = __builtin_amdgcn_mfma_f32_32x32x16_bf16(kf, qf[kc], s2[tt], 0, 0, 0);
          }
        __builtin_amdgcn_s_setprio(0);

        // causal mask (only tiles overlapping this wave's diagonal)
        const int kv0 = jt * 64;
        if (kv0 + 63 > q0 + w * 32) {
          const int thr = qrow - kv0 - 4 * hi;
#pragma unroll
          for (int tt = 0; tt < 2; tt++)
#pragma unroll
            for (int i = 0; i < 16; i++) {
              const int kvoff = tt * 32 + (i & 3) + 8 * (i >> 2);
              s2[tt][i] = (kvoff > thr) ? -1e30f : s2[tt][i];
            }
        }

        // row max: in-lane tree + cross-half shfl
        float mx;
        {
          float m8[8];
#pragma unroll
          for (int i = 0; i < 8; i++)
            m8[i] = fmaxf(fmaxf(s2[0][i], s2[0][i + 8]), fmaxf(s2[1][i], s2[1][i + 8]));
#pragma unroll
          for (int st = 4; st > 0; st >>= 1)
#pragma unroll
            for (int i = 0; i < st; i++) m8[i] = fmaxf(m8[i], m8[i + st]);
          mx = m8[0];
        }
        mx = fmaxf(mx, __shfl_xor(mx, 32));

        // defer-max: only rescale when some row's max grew by >8 (2^8 P-bound)
        if (__any(mx > m_run + 8.0f)) {
          const float mnew = fmaxf(m_run, mx);
          const float corr = __builtin_amdgcn_exp2f(m_run - mnew);
          m_run = mnew;
          l_run *= corr;
#pragma unroll
          for (int od = 0; od < 2; od++)
#pragma unroll
            for (int i = 0; i < 16; i++) oacc[od][i] *= corr;
        }

        // p = exp2(s - m)   (logits pre-scaled by log2e at the Q projection)
#pragma unroll
        for (int tt = 0; tt < 2; tt++)
#pragma unroll
          for (int i = 0; i < 16; i++)
            s2[tt][i] = __builtin_amdgcn_exp2f(s2[tt][i] - m_run);

        // row sum: in-lane tree + cross-half shfl
        float rs;
        {
          float a8[8];
#pragma unroll
          for (int i = 0; i < 8; i++)
            a8[i] = (s2[0][i] + s2[0][i + 8]) + (s2[1][i] + s2[1][i + 8]);
#pragma unroll
          for (int st = 4; st > 0; st >>= 1)
#pragma unroll
            for (int i = 0; i < st; i++) a8[i] += a8[i + st];
          rs = a8[0];
        }
        rs += __shfl_xor(rs, 32);
        l_run += rs;

        // build P B-operand fragments: pa[ks] holds kv = ks*16 + hi*8 + j
        union U8 { uint4 u; bf16x8 v; } pa[4];
#pragma unroll
        for (int ks = 0; ks < 4; ks++) {
          const int tt = ks >> 1, b0 = (ks & 1) * 8;
          const unsigned int w0 = pack2(s2[tt][b0 + 0], s2[tt][b0 + 1]);
          const unsigned int w1 = pack2(s2[tt][b0 + 2], s2[tt][b0 + 3]);
          const unsigned int w2 = pack2(s2[tt][b0 + 4], s2[tt][b0 + 5]);
          const unsigned int w3 = pack2(s2[tt][b0 + 6], s2[tt][b0 + 7]);
          const unsigned int p0 = (unsigned int)__shfl_xor((int)w0, 32);
          const unsigned int p1 = (unsigned int)__shfl_xor((int)w1, 32);
          const unsigned int p2 = (unsigned int)__shfl_xor((int)w2, 32);
          const unsigned int p3 = (unsigned int)__shfl_xor((int)w3, 32);
          pa[ks].u = hi ? make_uint4(p2, p3, w2, w3) : make_uint4(w0, w1, p0, p1);
        }

        // O^T += VT * P : D[dh][q]
        __builtin_amdgcn_s_setprio(1);
#pragma unroll
        for (int od = 0; od < 2; od++)
#pragma unroll
          for (int ks = 0; ks < 4; ks++) {
            bf16x8 vf = *(const bf16x8*)&VTs[cur][od * 32 + lo5][ks * 16 + hi * 8];
            oacc[od] = __builtin_amdgcn_mfma_f32_32x32x16_bf16(vf, pa[ks].v, oacc[od], 0, 0, 0);
          }
        __builtin_amdgcn_s_setprio(0);
      }

      // stage next tile into the other buffer (visible after next barrier)
      if (jt + 1 < ntiles) {
        *(uint4*)&Ks[cur ^ 1][rA][kA] = kr0;
        *(uint4*)&Ks[cur ^ 1][rB][kA] = kr1;
        *(uint4*)&VTs[cur ^ 1][rA][kA] = vr0;
        *(uint4*)&VTs[cur ^ 1][rB][kA] = vr1;
      }
    }

    // epilogue: O[b][l][h*64+dh] bf16; lane's q = qrow, dh = crow+od*32
    const float linv = 1.f / l_run;
    unsigned short* Ob = O + ((size_t)(b * LL + qrow) * DM) + h * DH;
#pragma unroll
    for (int od = 0; od < 2; od++)
#pragma unroll
      for (int m = 0; m < 8; m++) {
        const int dh0 = od * 32 + ((2 * m) & 3) + 8 * ((2 * m) >> 2) + 4 * hi;
        const unsigned int pk =
            pack2(oacc[od][2 * m] * linv, oacc[od][2 * m + 1] * linv);
        *(unsigned int*)(Ob + dh0) = pk;
      }
  }
}

// ---------------------------------------------------------------------------
extern "C" void kernel_launch(void* const* d_in, const int* in_sizes, int n_in,
                              void* d_out, int out_size, void* d_ws, size_t ws_size,
                              hipStream_t stream) {
  (void)in_sizes; (void)n_in; (void)out_size; (void)ws_size;
  const float* q  = (const float*)d_in[0];
  const float* k  = (const float*)d_in[1];
  const float* v  = (const float*)d_in[2];
  const float* Wq = (const float*)d_in[3];
  const float* bq = (const float*)d_in[4];
  const float* Wk = (const float*)d_in[5];
  const float* bk = (const float*)d_in[6];
  const float* Wv = (const float*)d_in[7];
  const float* bv = (const float*)d_in[8];
  const float* Wo = (const float*)d_in[9];
  const float* bo = (const float*)d_in[10];

  char* ws = (char*)d_ws;
  const size_t WSZ = (size_t)DM * DM * 2;          // 2 MB per transposed weight
  const size_t HSZ = (size_t)MROWS * DM * 2;       // 16 MB per bf16 activation
  unsigned short* WqT = (unsigned short*)(ws);
  unsigned short* WkT = (unsigned short*)(ws + WSZ);
  unsigned short* WvT = (unsigned short*)(ws + 2 * WSZ);
  unsigned short* WoT = (unsigned short*)(ws + 3 * WSZ);
  unsigned short* Qh  = (unsigned short*)(ws + 4 * WSZ);
  unsigned short* Kh  = (unsigned short*)(ws + 4 * WSZ + HSZ);
  unsigned short* VhT = (unsigned short*)(ws + 4 * WSZ + 2 * HSZ);
  unsigned short* X   = (unsigned short*)(ws + 4 * WSZ + 3 * HSZ);  // cvt scratch, later Oc
  unsigned short* Oc  = X;  // safe: X's cvt contents dead once V-GEMM finishes

  transpose_w_kernel<<<dim3(32, 32, 4), 256, 0, stream>>>(
      Wq, Wk, Wv, Wo, WqT, WkT, WvT, WoT);

  const dim3 cgrid(MROWS * DM / (256 * 8));
  const dim3 ggrid(DM / 128, MROWS / 128);

  cvt_bf16_kernel<<<cgrid, 256, 0, stream>>>(q, X);
  gemm_bf16_kernel<0><<<ggrid, 256, 0, stream>>>(X, WqT, bq, Qh, QSCALE);
  cvt_bf16_kernel<<<cgrid, 256, 0, stream>>>(k, X);
  gemm_bf16_kernel<0><<<ggrid, 256, 0, stream>>>(X, WkT, bk, Kh, 1.0f);
  cvt_bf16_kernel<<<cgrid, 256, 0, stream>>>(v, X);
  gemm_bf16_kernel<2><<<ggrid, 256, 0, stream>>>(X, WvT, bv, VhT, 1.0f);

  attn_kernel<<<dim3(8, BB * HEADS), 256, 0, stream>>>(Qh, Kh, VhT, Oc);

  gemm_bf16_kernel<1><<<ggrid, 256, 0, stream>>>(Oc, WoT, bo, (float*)d_out, 1.0f);
}